// Round 15
// baseline (304.065 us; speedup 1.0000x reference)
//
#include <hip/hip_runtime.h>
#include <stdint.h>

// ---------------------------------------------------------------------------
// Encoder block, MI355X bf16-MFMA (round 15: attention de-staged -- K/V read
// directly from L2 per-fragment, Q in registers, per-wave Ps, ZERO barriers
// in the K-loop, 3 blocks/CU).  GEMMs = round 13 (banded map, counted vmcnt).
// Quirks: k = q (query projection), scale = 768^-0.5.
// ---------------------------------------------------------------------------

typedef __attribute__((ext_vector_type(8))) short s8v;      // 8 x bf16
typedef __attribute__((ext_vector_type(4))) float f32x4;    // MFMA C/D frag
typedef __attribute__((ext_vector_type(4))) unsigned short us4v;

__device__ __forceinline__ unsigned short f2b(float f) {  // f32 -> bf16 RTNE
  union { float f; unsigned u; } v; v.f = f;
  unsigned r = v.u + 0x7FFFu + ((v.u >> 16) & 1u);
  return (unsigned short)(r >> 16);
}

__device__ __forceinline__ void g2l16(const unsigned short* g, unsigned short* l) {
  __builtin_amdgcn_global_load_lds(
      (const __attribute__((address_space(1))) unsigned int*)g,
      (__attribute__((address_space(3))) unsigned int*)l, 16, 0, 0);
}

// sqrt(768^-0.5 * log2(e)): folded into BOTH q and k (same tensor, k=q quirk)
#define QSCALE 0.22816534f

// ---------------- weight repack: all weights -> bf16, B^T [N][K] layout ------
__global__ __launch_bounds__(256) void repack_kernel(
    const float* __restrict__ Wq, const float* __restrict__ bq,
    const float* __restrict__ Wv, const float* __restrict__ bv,
    const float* __restrict__ Wo, const float* __restrict__ W1,
    const float* __restrict__ W2,
    unsigned short* __restrict__ Wqv_t, float* __restrict__ bias_qv,
    unsigned short* __restrict__ Wo_t, unsigned short* __restrict__ W1_t,
    unsigned short* __restrict__ W2_t)
{
  int i = blockIdx.x * 256 + threadIdx.x;
  if (i < 1536 * 768) {
    int n = i / 768, d = i % 768;
    float val;
    if (n < 768) { int h = n >> 6, e = n & 63; val = Wq[(h * 768 + d) * 64 + e] * QSCALE; }
    else { int c = n - 768; int h = c >> 6, e = c & 63; val = Wv[(h * 768 + d) * 64 + e]; }
    Wqv_t[i] = f2b(val);
  }
  if (i < 1536) bias_qv[i] = (i < 768) ? bq[i] * QSCALE : bv[i - 768];
  if (i < 768 * 768)  { int n = i / 768,  k = i % 768;  Wo_t[i] = f2b(Wo[k * 768  + n]); }
  if (i < 3072 * 768) { int n = i / 768,  k = i % 768;  W1_t[i] = f2b(W1[k * 3072 + n]); }
  if (i < 768 * 3072) { int n = i / 3072, k = i % 3072; W2_t[i] = f2b(W2[k * 768  + n]); }
}

// ---------------- LayerNorm: f32 [8192][768] -> bf16 ------------------------
__global__ __launch_bounds__(256) void ln_kernel(
    const float* __restrict__ x, const float* __restrict__ g,
    const float* __restrict__ b, unsigned short* __restrict__ out)
{
  __shared__ float red[4], red2[4];
  int row = blockIdx.x, t = threadIdx.x;
  const float* xr = x + (size_t)row * 768;
  float v0 = xr[t], v1 = xr[t + 256], v2 = xr[t + 512];
  float s = v0 + v1 + v2;
  #pragma unroll
  for (int m = 32; m; m >>= 1) s += __shfl_xor(s, m);
  if ((t & 63) == 0) red[t >> 6] = s;
  __syncthreads();
  float mean = (red[0] + red[1] + red[2] + red[3]) * (1.f / 768.f);
  float d0 = v0 - mean, d1 = v1 - mean, d2 = v2 - mean;
  float vs = d0 * d0 + d1 * d1 + d2 * d2;
  #pragma unroll
  for (int m = 32; m; m >>= 1) vs += __shfl_xor(vs, m);
  if ((t & 63) == 0) red2[t >> 6] = vs;
  __syncthreads();
  float var = (red2[0] + red2[1] + red2[2] + red2[3]) * (1.f / 768.f);
  float rs = rsqrtf(var + 1e-5f);
  unsigned short* o = out + (size_t)row * 768;
  o[t]       = f2b(d0 * rs * g[t]       + b[t]);
  o[t + 256] = f2b(d1 * rs * g[t + 256] + b[t + 256]);
  o[t + 512] = f2b(d2 * rs * g[t + 512] + b[t + 512]);
}

// banded within-chunk map: bands of BAND m-tiles, n swept per band, m fastest
template<int NTN, int BAND>
__device__ __forceinline__ void band_map(int bid, int grid, int& m_t, int& n_t) {
  int q8 = grid >> 3;
  int mb = q8 / NTN;
  int xcd = bid & 7, idx = bid >> 3;
  int pb = BAND * NTN;
  int band = idx / pb, r = idx % pb;
  m_t = xcd * mb + band * BAND + (r % BAND);
  n_t = r / BAND;
}

// ---------------- 8-wave 128x128 2-buf counted-vmcnt GEMM --------------------
// EPI: 1 = f32 out = resid + acc + bias; 2 = bf16 tanh-gelu; 3 = qv split.
template<int EPI, int N, int K>
__global__ __launch_bounds__(512, 4) void gemm128(
    const unsigned short* __restrict__ A, const unsigned short* __restrict__ Bt,
    const float* __restrict__ bias,
    const float* resid, float* out_f32,
    unsigned short* __restrict__ out_bf,
    unsigned short* __restrict__ q_out, unsigned short* __restrict__ vt_out)
{
  __shared__ __align__(16) unsigned short As_[2][8192];
  __shared__ __align__(16) unsigned short Bs_[2][8192];
  constexpr int NTN = N >> 7;
  constexpr int NT = K >> 6;
  int m_t, n_t;
  band_map<NTN, 4>(blockIdx.x, gridDim.x, m_t, n_t);
  int m0 = m_t << 7, n0 = n_t << 7;
  int t = threadIdx.x, lane = t & 63, w = t >> 6;  // w 0..7
  int l15 = lane & 15, lg = lane >> 4;
  int wm = (w >> 2) << 6;                       // 0 / 64
  int wn = (w & 3) << 5;                        // 0 / 32 / 64 / 96
  int lrow = lane >> 3;                         // 0..7
  int lxor = ((lane & 7) ^ lrow) << 3;          // pre-swizzled src col (ushort)
  const unsigned short* Abase = A + (size_t)m0 * K;
  const unsigned short* Bbase = Bt + (size_t)n0 * K;

  auto stage = [&](int buf, int tile) {
    int k0 = tile << 6;
    #pragma unroll
    for (int j = 0; j < 2; ++j) {               // 4 loads/thread: A,B x j
      int row = j * 64 + w * 8 + lrow;
      int doff = (j * 512 + w * 64) * 8;        // wave-uniform dest (ushort)
      g2l16(&Abase[(size_t)row * K + k0 + lxor], &As_[buf][doff]);
      g2l16(&Bbase[(size_t)row * K + k0 + lxor], &Bs_[buf][doff]);
    }
  };

  f32x4 acc[4][2] = {};
  stage(0, 0);
  asm volatile("s_waitcnt vmcnt(0)" ::: "memory");
  __builtin_amdgcn_sched_barrier(0);
  __builtin_amdgcn_s_barrier();

  int cswz = (l15 & 7) << 3;
  for (int tt = 0; tt < NT; ++tt) {
    int cur = tt & 1;
    if (tt + 1 < NT) {
      stage(cur ^ 1, tt + 1);
      asm volatile("s_waitcnt vmcnt(4)" ::: "memory");
    } else {
      asm volatile("s_waitcnt vmcnt(0)" ::: "memory");
    }
    __builtin_amdgcn_sched_barrier(0);
    __builtin_amdgcn_s_barrier();          // all waves' stage(tt) landed
    __builtin_amdgcn_sched_barrier(0);
    const unsigned short* Ac = &As_[cur][0];
    const unsigned short* Bc = &Bs_[cur][0];
    #pragma unroll
    for (int kk = 0; kk < 2; ++kk) {
      s8v a[4], b[2];
      int col = (kk * 32 + lg * 8) ^ cswz;
      #pragma unroll
      for (int i = 0; i < 4; ++i)
        a[i] = *(const s8v*)&Ac[(wm + i * 16 + l15) * 64 + col];
      #pragma unroll
      for (int i = 0; i < 2; ++i)
        b[i] = *(const s8v*)&Bc[(wn + i * 16 + l15) * 64 + col];
      __builtin_amdgcn_s_setprio(1);
      #pragma unroll
      for (int mi = 0; mi < 4; ++mi)
        #pragma unroll
        for (int ni = 0; ni < 2; ++ni)
          acc[mi][ni] = __builtin_amdgcn_mfma_f32_16x16x32_bf16(a[mi], b[ni], acc[mi][ni], 0, 0, 0);
      __builtin_amdgcn_s_setprio(0);
    }
    if (tt + 1 < NT) {
      __builtin_amdgcn_sched_barrier(0);
      __builtin_amdgcn_s_barrier();        // reads of buf cur done block-wide
      __builtin_amdgcn_sched_barrier(0);
    }
  }
  // ---- epilogue ----
  #pragma unroll
  for (int mi = 0; mi < 4; ++mi) {
    #pragma unroll
    for (int ni = 0; ni < 2; ++ni) {
      int col = n0 + wn + ni * 16 + l15;
      float bs = bias[col];
      #pragma unroll
      for (int r = 0; r < 4; ++r) {
        int row = m0 + wm + mi * 16 + lg * 4 + r;
        float v = acc[mi][ni][r] + bs;
        if (EPI == 1) {
          out_f32[(size_t)row * N + col] = resid[(size_t)row * N + col] + v;
        } else if (EPI == 2) {
          // tanh-gelu via exp2: v * sigmoid(1.5957688(v + 0.044715 v^3))
          float v2 = v * v;
          float z = v * fmaf(-0.10294202f, v2, -2.302026f);
          float e; asm("v_exp_f32 %0, %1" : "=v"(e) : "v"(z));
          float rcp; asm("v_rcp_f32 %0, %1" : "=v"(rcp) : "v"(e + 1.0f));
          out_bf[(size_t)row * N + col] = f2b(v * rcp);
        } else { // EPI == 3
          if (col < 768) {
            q_out[(size_t)row * 768 + col] = f2b(v);
          } else {
            int c = col - 768; int hh = c >> 6, e = c & 63;
            int bb = row >> 10, s = row & 1023;
            vt_out[(((size_t)(bb * 12 + hh)) * 64 + e) * 1024 + s] = f2b(v);
          }
        }
      }
    }
  }
}

// ---------------- FC2 variant: 128x64 tile, 3 blocks/CU ----------------------
template<int N, int K>
__global__ __launch_bounds__(512, 6) void gemm_n64(
    const unsigned short* __restrict__ A, const unsigned short* __restrict__ Bt,
    const float* __restrict__ bias, const float* resid, float* out_f32)
{
  __shared__ __align__(16) unsigned short As_[2][8192];   // 128x64
  __shared__ __align__(16) unsigned short Bs_[2][4096];   // 64x64
  constexpr int NTN = N >> 6;
  constexpr int NT = K >> 6;
  int m_t, n_t;
  band_map<NTN, 4>(blockIdx.x, gridDim.x, m_t, n_t);
  int m0 = m_t << 7, n0 = n_t << 6;
  int t = threadIdx.x, lane = t & 63, w = t >> 6;
  int l15 = lane & 15, lg = lane >> 4;
  int wm = (w >> 1) << 5;                       // 0/32/64/96
  int wn = (w & 1) << 5;                        // 0/32
  int lrow = lane >> 3;
  int lxor = ((lane & 7) ^ lrow) << 3;
  const unsigned short* Abase = A + (size_t)m0 * K;
  const unsigned short* Bbase = Bt + (size_t)n0 * K;

  auto stage = [&](int buf, int tile) {
    int k0 = tile << 6;
    #pragma unroll
    for (int j = 0; j < 2; ++j) {               // A: 2 loads/thread
      int row = j * 64 + w * 8 + lrow;
      g2l16(&Abase[(size_t)row * K + k0 + lxor], &As_[buf][(j * 512 + w * 64) * 8]);
    }
    int brow = w * 8 + lrow;                    // B: 1 load/thread
    g2l16(&Bbase[(size_t)brow * K + k0 + lxor], &Bs_[buf][w * 512]);
  };

  f32x4 acc[2][2] = {};
  stage(0, 0);
  asm volatile("s_waitcnt vmcnt(0)" ::: "memory");
  __builtin_amdgcn_sched_barrier(0);
  __builtin_amdgcn_s_barrier();

  int cswz = (l15 & 7) << 3;
  for (int tt = 0; tt < NT; ++tt) {
    int cur = tt & 1;
    if (tt + 1 < NT) {
      stage(cur ^ 1, tt + 1);
      asm volatile("s_waitcnt vmcnt(3)" ::: "memory");
    } else {
      asm volatile("s_waitcnt vmcnt(0)" ::: "memory");
    }
    __builtin_amdgcn_sched_barrier(0);
    __builtin_amdgcn_s_barrier();
    __builtin_amdgcn_sched_barrier(0);
    const unsigned short* Ac = &As_[cur][0];
    const unsigned short* Bc = &Bs_[cur][0];
    #pragma unroll
    for (int kk = 0; kk < 2; ++kk) {
      s8v a[2], b[2];
      int col = (kk * 32 + lg * 8) ^ cswz;
      #pragma unroll
      for (int i = 0; i < 2; ++i)
        a[i] = *(const s8v*)&Ac[(wm + i * 16 + l15) * 64 + col];
      #pragma unroll
      for (int i = 0; i < 2; ++i)
        b[i] = *(const s8v*)&Bc[(wn + i * 16 + l15) * 64 + col];
      __builtin_amdgcn_s_setprio(1);
      #pragma unroll
      for (int mi = 0; mi < 2; ++mi)
        #pragma unroll
        for (int ni = 0; ni < 2; ++ni)
          acc[mi][ni] = __builtin_amdgcn_mfma_f32_16x16x32_bf16(a[mi], b[ni], acc[mi][ni], 0, 0, 0);
      __builtin_amdgcn_s_setprio(0);
    }
    if (tt + 1 < NT) {
      __builtin_amdgcn_sched_barrier(0);
      __builtin_amdgcn_s_barrier();
      __builtin_amdgcn_sched_barrier(0);
    }
  }
  #pragma unroll
  for (int mi = 0; mi < 2; ++mi) {
    #pragma unroll
    for (int ni = 0; ni < 2; ++ni) {
      int col = n0 + wn + ni * 16 + l15;
      float bs = bias[col];
      #pragma unroll
      for (int r = 0; r < 4; ++r) {
        int row = m0 + wm + mi * 16 + lg * 4 + r;
        float v = acc[mi][ni][r] + bs;
        out_f32[(size_t)row * N + col] = resid[(size_t)row * N + col] + v;
      }
    }
  }
}

// ---------------- fused attention, de-staged (k = q quirk) -------------------
// 768 blocks XCD-chunked; 4 waves x 32 q-cols; 3 blocks/CU (16 KiB LDS).
// K/V fragments read directly from global (L2-hot: 12 bh/XCD = 3 MB < 4 MB).
// Q fragments in registers (loaded once).  Ps is PER-WAVE -> no barriers in
// the K-loop at all; waves run fully independent.
__global__ __launch_bounds__(256, 3) void attn_kernel(
    const unsigned short* __restrict__ qk,  // [8192][768] (q == k, pre-scaled)
    const unsigned short* __restrict__ vt,  // [96][64][1024]
    unsigned short* __restrict__ o)         // [8192][768]
{
  __shared__ __align__(16) unsigned short Ps[4][32 * 64];  // per-wave P tile
  int bid = blockIdx.x;
  int xcd = bid & 7, idx = bid >> 3;
  int bh = xcd * 12 + (idx >> 3), qt = idx & 7;
  int b = bh / 12, h = bh % 12;
  int t = threadIdx.x, lane = t & 63, w = t >> 6;
  int l15 = lane & 15, lg = lane >> 4;
  int wq0 = w << 5;
  size_t qrow0 = (size_t)b * 1024 + qt * 128;
  size_t krow0 = (size_t)b * 1024;
  size_t vbase = ((size_t)bh) * 64 * 1024;
  int cswz = (l15 & 7) << 3;
  unsigned short* myPs = &Ps[w][0];

  // Q fragments in registers (reused for all 16 K-tiles)
  s8v qf[2][2];
  #pragma unroll
  for (int ni = 0; ni < 2; ++ni)
    #pragma unroll
    for (int kk = 0; kk < 2; ++kk)
      qf[ni][kk] = *(const s8v*)&qk[(qrow0 + wq0 + ni * 16 + l15) * 768 +
                                    h * 64 + kk * 32 + lg * 8];

  f32x4 oacc[4][2] = {};
  float lsum[2] = {0.f, 0.f};

  for (int kt = 0; kt < 16; ++kt) {
    // K fragments straight from L2
    s8v a[4][2];
    #pragma unroll
    for (int i = 0; i < 4; ++i)
      #pragma unroll
      for (int kk = 0; kk < 2; ++kk)
        a[i][kk] = *(const s8v*)&qk[(krow0 + kt * 64 + i * 16 + l15) * 768 +
                                    h * 64 + kk * 32 + lg * 8];
    // S^T = K * Q^T  (pre-scaled into log2 domain)
    f32x4 st[4][2] = {};
    #pragma unroll
    for (int kk = 0; kk < 2; ++kk)
      #pragma unroll
      for (int mi = 0; mi < 4; ++mi)
        #pragma unroll
        for (int ni = 0; ni < 2; ++ni)
          st[mi][ni] = __builtin_amdgcn_mfma_f32_16x16x32_bf16(a[mi][kk], qf[ni][kk], st[mi][ni], 0, 0, 0);
    // P = 2^st -> bf16 pairs -> own-wave Ps rows
    #pragma unroll
    for (int ni = 0; ni < 2; ++ni) {
      int prow = (ni * 16 + l15) * 64;
      #pragma unroll
      for (int mi = 0; mi < 4; ++mi) {
        float p0, p1, p2, p3;
        asm("v_exp_f32 %0, %1" : "=v"(p0) : "v"(st[mi][ni][0]));
        asm("v_exp_f32 %0, %1" : "=v"(p1) : "v"(st[mi][ni][1]));
        asm("v_exp_f32 %0, %1" : "=v"(p2) : "v"(st[mi][ni][2]));
        asm("v_exp_f32 %0, %1" : "=v"(p3) : "v"(st[mi][ni][3]));
        lsum[ni] += (p0 + p1) + (p2 + p3);
        unsigned lo, hi;
        asm("v_cvt_pk_bf16_f32 %0, %1, %2" : "=v"(lo) : "v"(p0), "v"(p1));
        asm("v_cvt_pk_bf16_f32 %0, %1, %2" : "=v"(hi) : "v"(p2), "v"(p3));
        unsigned long long pk = (unsigned long long)lo | ((unsigned long long)hi << 32);
        *(unsigned long long*)&myPs[prow + ((mi * 16 + lg * 4) ^ cswz)] = pk;
      }
    }
    // V fragments straight from L2; PV: o^T += V^T * P^T (own-wave Ps reads)
    #pragma unroll
    for (int kk = 0; kk < 2; ++kk) {
      int col = (kk * 32 + lg * 8) ^ cswz;
      s8v vv[4], bp[2];
      #pragma unroll
      for (int i = 0; i < 4; ++i)
        vv[i] = *(const s8v*)&vt[vbase + (size_t)(i * 16 + l15) * 1024 +
                                 kt * 64 + kk * 32 + lg * 8];
      #pragma unroll
      for (int i = 0; i < 2; ++i)
        bp[i] = *(const s8v*)&myPs[(i * 16 + l15) * 64 + col];
      #pragma unroll
      for (int ei = 0; ei < 4; ++ei)
        #pragma unroll
        for (int ni = 0; ni < 2; ++ni)
          oacc[ei][ni] = __builtin_amdgcn_mfma_f32_16x16x32_bf16(vv[ei], bp[ni], oacc[ei][ni], 0, 0, 0);
    }
  }
  // finalize: reduce lsum across lg groups, normalize, write o
  #pragma unroll
  for (int ni = 0; ni < 2; ++ni) {
    float s = lsum[ni];
    s += __shfl_xor(s, 16);
    s += __shfl_xor(s, 32);
    float inv = 1.f / s;
    int q = wq0 + ni * 16 + l15;
    size_t obase = (qrow0 + q) * 768 + h * 64;
    #pragma unroll
    for (int ei = 0; ei < 4; ++ei) {
      us4v ov;
      #pragma unroll
      for (int r = 0; r < 4; ++r) ov[r] = f2b(oacc[ei][ni][r] * inv);
      *(us4v*)&o[obase + ei * 16 + lg * 4] = ov;
    }
  }
}

// ---------------------------------------------------------------------------
extern "C" void kernel_launch(void* const* d_in, const int* in_sizes, int n_in,
                              void* d_out, int out_size, void* d_ws, size_t ws_size,
                              hipStream_t stream)
{
  const float* x     = (const float*)d_in[0];
  const float* ln1_g = (const float*)d_in[1];
  const float* ln1_b = (const float*)d_in[2];
  const float* Wq    = (const float*)d_in[3];
  const float* bq    = (const float*)d_in[4];
  const float* Wv    = (const float*)d_in[5];
  const float* bv    = (const float*)d_in[6];
  const float* Wo    = (const float*)d_in[7];
  const float* bo    = (const float*)d_in[8];
  const float* ln2_g = (const float*)d_in[9];
  const float* ln2_b = (const float*)d_in[10];
  const float* W1    = (const float*)d_in[11];
  const float* b1    = (const float*)d_in[12];
  const float* W2    = (const float*)d_in[13];
  const float* b2    = (const float*)d_in[14];
  float* out = (float*)d_out;

  char* ws = (char*)d_ws;
  size_t off = 0;
  auto alloc = [&](size_t bytes) -> void* {
    void* p = ws + off; off += (bytes + 255) & ~(size_t)255; return p;
  };
  unsigned short* Wqv_t  = (unsigned short*)alloc(1536ull * 768 * 2);
  float*          bias_qv= (float*)         alloc(1536ull * 4);
  unsigned short* Wo_t   = (unsigned short*)alloc(768ull * 768 * 2);
  unsigned short* W1_t   = (unsigned short*)alloc(3072ull * 768 * 2);
  unsigned short* W2_t   = (unsigned short*)alloc(768ull * 3072 * 2);
  unsigned short* h_bf   = (unsigned short*)alloc(8192ull * 768 * 2);
  unsigned short* q_bf   = (unsigned short*)alloc(8192ull * 768 * 2);
  unsigned short* v_t    = (unsigned short*)alloc(96ull * 64 * 1024 * 2);
  unsigned short* o_bf   = (unsigned short*)alloc(8192ull * 768 * 2);
  unsigned short* h2_bf  = (unsigned short*)alloc(8192ull * 768 * 2);
  unsigned short* m1_bf  = (unsigned short*)alloc(8192ull * 3072 * 2);

  repack_kernel<<<9216, 256, 0, stream>>>(Wq, bq, Wv, bv, Wo, W1, W2,
                                          Wqv_t, bias_qv, Wo_t, W1_t, W2_t);
  ln_kernel<<<8192, 256, 0, stream>>>(x, ln1_g, ln1_b, h_bf);
  gemm128<3, 1536, 768><<<768, 512, 0, stream>>>(h_bf, Wqv_t, bias_qv,
      nullptr, nullptr, nullptr, q_bf, v_t);
  attn_kernel<<<768, 256, 0, stream>>>(q_bf, v_t, o_bf);
  gemm128<1, 768, 768><<<384, 512, 0, stream>>>(o_bf, Wo_t, bo,
      x, out, nullptr, nullptr, nullptr);
  ln_kernel<<<8192, 256, 0, stream>>>(out, ln2_g, ln2_b, h2_bf);
  gemm128<2, 3072, 768><<<1536, 512, 0, stream>>>(h2_bf, W1_t, b1,
      nullptr, nullptr, m1_bf, nullptr, nullptr);
  gemm_n64<768, 3072><<<768, 512, 0, stream>>>(m1_bf, W2_t, b2, out, out);
}

// Round 16
// 251.383 us; speedup vs baseline: 1.2096x; 1.2096x over previous
//
#include <hip/hip_runtime.h>
#include <stdint.h>

// ---------------------------------------------------------------------------
// Encoder block, MI355X bf16-MFMA (round 16: staged attention with counted
// vmcnt(4) pipeline, Q in registers, per-wave Ps, 48 KiB LDS -> 3 blocks/CU).
// GEMMs = round 13/14 (banded map, counted vmcnt).  Quirks: k = q, 768^-0.5.
// ---------------------------------------------------------------------------

typedef __attribute__((ext_vector_type(8))) short s8v;      // 8 x bf16
typedef __attribute__((ext_vector_type(4))) float f32x4;    // MFMA C/D frag
typedef __attribute__((ext_vector_type(4))) unsigned short us4v;

__device__ __forceinline__ unsigned short f2b(float f) {  // f32 -> bf16 RTNE
  union { float f; unsigned u; } v; v.f = f;
  unsigned r = v.u + 0x7FFFu + ((v.u >> 16) & 1u);
  return (unsigned short)(r >> 16);
}

__device__ __forceinline__ void g2l16(const unsigned short* g, unsigned short* l) {
  __builtin_amdgcn_global_load_lds(
      (const __attribute__((address_space(1))) unsigned int*)g,
      (__attribute__((address_space(3))) unsigned int*)l, 16, 0, 0);
}

// sqrt(768^-0.5 * log2(e)): folded into BOTH q and k (same tensor, k=q quirk)
#define QSCALE 0.22816534f

// ---------------- weight repack: all weights -> bf16, B^T [N][K] layout ------
__global__ __launch_bounds__(256) void repack_kernel(
    const float* __restrict__ Wq, const float* __restrict__ bq,
    const float* __restrict__ Wv, const float* __restrict__ bv,
    const float* __restrict__ Wo, const float* __restrict__ W1,
    const float* __restrict__ W2,
    unsigned short* __restrict__ Wqv_t, float* __restrict__ bias_qv,
    unsigned short* __restrict__ Wo_t, unsigned short* __restrict__ W1_t,
    unsigned short* __restrict__ W2_t)
{
  int i = blockIdx.x * 256 + threadIdx.x;
  if (i < 1536 * 768) {
    int n = i / 768, d = i % 768;
    float val;
    if (n < 768) { int h = n >> 6, e = n & 63; val = Wq[(h * 768 + d) * 64 + e] * QSCALE; }
    else { int c = n - 768; int h = c >> 6, e = c & 63; val = Wv[(h * 768 + d) * 64 + e]; }
    Wqv_t[i] = f2b(val);
  }
  if (i < 1536) bias_qv[i] = (i < 768) ? bq[i] * QSCALE : bv[i - 768];
  if (i < 768 * 768)  { int n = i / 768,  k = i % 768;  Wo_t[i] = f2b(Wo[k * 768  + n]); }
  if (i < 3072 * 768) { int n = i / 768,  k = i % 768;  W1_t[i] = f2b(W1[k * 3072 + n]); }
  if (i < 768 * 3072) { int n = i / 3072, k = i % 3072; W2_t[i] = f2b(W2[k * 768  + n]); }
}

// ---------------- LayerNorm: f32 [8192][768] -> bf16 ------------------------
__global__ __launch_bounds__(256) void ln_kernel(
    const float* __restrict__ x, const float* __restrict__ g,
    const float* __restrict__ b, unsigned short* __restrict__ out)
{
  __shared__ float red[4], red2[4];
  int row = blockIdx.x, t = threadIdx.x;
  const float* xr = x + (size_t)row * 768;
  float v0 = xr[t], v1 = xr[t + 256], v2 = xr[t + 512];
  float s = v0 + v1 + v2;
  #pragma unroll
  for (int m = 32; m; m >>= 1) s += __shfl_xor(s, m);
  if ((t & 63) == 0) red[t >> 6] = s;
  __syncthreads();
  float mean = (red[0] + red[1] + red[2] + red[3]) * (1.f / 768.f);
  float d0 = v0 - mean, d1 = v1 - mean, d2 = v2 - mean;
  float vs = d0 * d0 + d1 * d1 + d2 * d2;
  #pragma unroll
  for (int m = 32; m; m >>= 1) vs += __shfl_xor(vs, m);
  if ((t & 63) == 0) red2[t >> 6] = vs;
  __syncthreads();
  float var = (red2[0] + red2[1] + red2[2] + red2[3]) * (1.f / 768.f);
  float rs = rsqrtf(var + 1e-5f);
  unsigned short* o = out + (size_t)row * 768;
  o[t]       = f2b(d0 * rs * g[t]       + b[t]);
  o[t + 256] = f2b(d1 * rs * g[t + 256] + b[t + 256]);
  o[t + 512] = f2b(d2 * rs * g[t + 512] + b[t + 512]);
}

// banded within-chunk map: bands of BAND m-tiles, n swept per band, m fastest
template<int NTN, int BAND>
__device__ __forceinline__ void band_map(int bid, int grid, int& m_t, int& n_t) {
  int q8 = grid >> 3;
  int mb = q8 / NTN;
  int xcd = bid & 7, idx = bid >> 3;
  int pb = BAND * NTN;
  int band = idx / pb, r = idx % pb;
  m_t = xcd * mb + band * BAND + (r % BAND);
  n_t = r / BAND;
}

// ---------------- 8-wave 128x128 2-buf counted-vmcnt GEMM --------------------
// EPI: 1 = f32 out = resid + acc + bias; 2 = bf16 tanh-gelu; 3 = qv split.
template<int EPI, int N, int K>
__global__ __launch_bounds__(512, 4) void gemm128(
    const unsigned short* __restrict__ A, const unsigned short* __restrict__ Bt,
    const float* __restrict__ bias,
    const float* resid, float* out_f32,
    unsigned short* __restrict__ out_bf,
    unsigned short* __restrict__ q_out, unsigned short* __restrict__ vt_out)
{
  __shared__ __align__(16) unsigned short As_[2][8192];
  __shared__ __align__(16) unsigned short Bs_[2][8192];
  constexpr int NTN = N >> 7;
  constexpr int NT = K >> 6;
  int m_t, n_t;
  band_map<NTN, 4>(blockIdx.x, gridDim.x, m_t, n_t);
  int m0 = m_t << 7, n0 = n_t << 7;
  int t = threadIdx.x, lane = t & 63, w = t >> 6;  // w 0..7
  int l15 = lane & 15, lg = lane >> 4;
  int wm = (w >> 2) << 6;                       // 0 / 64
  int wn = (w & 3) << 5;                        // 0 / 32 / 64 / 96
  int lrow = lane >> 3;                         // 0..7
  int lxor = ((lane & 7) ^ lrow) << 3;          // pre-swizzled src col (ushort)
  const unsigned short* Abase = A + (size_t)m0 * K;
  const unsigned short* Bbase = Bt + (size_t)n0 * K;

  auto stage = [&](int buf, int tile) {
    int k0 = tile << 6;
    #pragma unroll
    for (int j = 0; j < 2; ++j) {               // 4 loads/thread: A,B x j
      int row = j * 64 + w * 8 + lrow;
      int doff = (j * 512 + w * 64) * 8;        // wave-uniform dest (ushort)
      g2l16(&Abase[(size_t)row * K + k0 + lxor], &As_[buf][doff]);
      g2l16(&Bbase[(size_t)row * K + k0 + lxor], &Bs_[buf][doff]);
    }
  };

  f32x4 acc[4][2] = {};
  stage(0, 0);
  asm volatile("s_waitcnt vmcnt(0)" ::: "memory");
  __builtin_amdgcn_sched_barrier(0);
  __builtin_amdgcn_s_barrier();

  int cswz = (l15 & 7) << 3;
  for (int tt = 0; tt < NT; ++tt) {
    int cur = tt & 1;
    if (tt + 1 < NT) {
      stage(cur ^ 1, tt + 1);
      asm volatile("s_waitcnt vmcnt(4)" ::: "memory");
    } else {
      asm volatile("s_waitcnt vmcnt(0)" ::: "memory");
    }
    __builtin_amdgcn_sched_barrier(0);
    __builtin_amdgcn_s_barrier();          // all waves' stage(tt) landed
    __builtin_amdgcn_sched_barrier(0);
    const unsigned short* Ac = &As_[cur][0];
    const unsigned short* Bc = &Bs_[cur][0];
    #pragma unroll
    for (int kk = 0; kk < 2; ++kk) {
      s8v a[4], b[2];
      int col = (kk * 32 + lg * 8) ^ cswz;
      #pragma unroll
      for (int i = 0; i < 4; ++i)
        a[i] = *(const s8v*)&Ac[(wm + i * 16 + l15) * 64 + col];
      #pragma unroll
      for (int i = 0; i < 2; ++i)
        b[i] = *(const s8v*)&Bc[(wn + i * 16 + l15) * 64 + col];
      __builtin_amdgcn_s_setprio(1);
      #pragma unroll
      for (int mi = 0; mi < 4; ++mi)
        #pragma unroll
        for (int ni = 0; ni < 2; ++ni)
          acc[mi][ni] = __builtin_amdgcn_mfma_f32_16x16x32_bf16(a[mi], b[ni], acc[mi][ni], 0, 0, 0);
      __builtin_amdgcn_s_setprio(0);
    }
    if (tt + 1 < NT) {
      __builtin_amdgcn_sched_barrier(0);
      __builtin_amdgcn_s_barrier();        // reads of buf cur done block-wide
      __builtin_amdgcn_sched_barrier(0);
    }
  }
  // ---- epilogue ----
  #pragma unroll
  for (int mi = 0; mi < 4; ++mi) {
    #pragma unroll
    for (int ni = 0; ni < 2; ++ni) {
      int col = n0 + wn + ni * 16 + l15;
      float bs = bias[col];
      #pragma unroll
      for (int r = 0; r < 4; ++r) {
        int row = m0 + wm + mi * 16 + lg * 4 + r;
        float v = acc[mi][ni][r] + bs;
        if (EPI == 1) {
          out_f32[(size_t)row * N + col] = resid[(size_t)row * N + col] + v;
        } else if (EPI == 2) {
          // tanh-gelu via exp2: v * sigmoid(1.5957688(v + 0.044715 v^3))
          float v2 = v * v;
          float z = v * fmaf(-0.10294202f, v2, -2.302026f);
          float e; asm("v_exp_f32 %0, %1" : "=v"(e) : "v"(z));
          float rcp; asm("v_rcp_f32 %0, %1" : "=v"(rcp) : "v"(e + 1.0f));
          out_bf[(size_t)row * N + col] = f2b(v * rcp);
        } else { // EPI == 3
          if (col < 768) {
            q_out[(size_t)row * 768 + col] = f2b(v);
          } else {
            int c = col - 768; int hh = c >> 6, e = c & 63;
            int bb = row >> 10, s = row & 1023;
            vt_out[(((size_t)(bb * 12 + hh)) * 64 + e) * 1024 + s] = f2b(v);
          }
        }
      }
    }
  }
}

// ---------------- FC2 variant: 128x64 tile, 3 blocks/CU ----------------------
template<int N, int K>
__global__ __launch_bounds__(512, 6) void gemm_n64(
    const unsigned short* __restrict__ A, const unsigned short* __restrict__ Bt,
    const float* __restrict__ bias, const float* resid, float* out_f32)
{
  __shared__ __align__(16) unsigned short As_[2][8192];   // 128x64
  __shared__ __align__(16) unsigned short Bs_[2][4096];   // 64x64
  constexpr int NTN = N >> 6;
  constexpr int NT = K >> 6;
  int m_t, n_t;
  band_map<NTN, 4>(blockIdx.x, gridDim.x, m_t, n_t);
  int m0 = m_t << 7, n0 = n_t << 6;
  int t = threadIdx.x, lane = t & 63, w = t >> 6;
  int l15 = lane & 15, lg = lane >> 4;
  int wm = (w >> 1) << 5;                       // 0/32/64/96
  int wn = (w & 1) << 5;                        // 0/32
  int lrow = lane >> 3;
  int lxor = ((lane & 7) ^ lrow) << 3;
  const unsigned short* Abase = A + (size_t)m0 * K;
  const unsigned short* Bbase = Bt + (size_t)n0 * K;

  auto stage = [&](int buf, int tile) {
    int k0 = tile << 6;
    #pragma unroll
    for (int j = 0; j < 2; ++j) {               // A: 2 loads/thread
      int row = j * 64 + w * 8 + lrow;
      g2l16(&Abase[(size_t)row * K + k0 + lxor], &As_[buf][(j * 512 + w * 64) * 8]);
    }
    int brow = w * 8 + lrow;                    // B: 1 load/thread
    g2l16(&Bbase[(size_t)brow * K + k0 + lxor], &Bs_[buf][w * 512]);
  };

  f32x4 acc[2][2] = {};
  stage(0, 0);
  asm volatile("s_waitcnt vmcnt(0)" ::: "memory");
  __builtin_amdgcn_sched_barrier(0);
  __builtin_amdgcn_s_barrier();

  int cswz = (l15 & 7) << 3;
  for (int tt = 0; tt < NT; ++tt) {
    int cur = tt & 1;
    if (tt + 1 < NT) {
      stage(cur ^ 1, tt + 1);
      asm volatile("s_waitcnt vmcnt(3)" ::: "memory");
    } else {
      asm volatile("s_waitcnt vmcnt(0)" ::: "memory");
    }
    __builtin_amdgcn_sched_barrier(0);
    __builtin_amdgcn_s_barrier();
    __builtin_amdgcn_sched_barrier(0);
    const unsigned short* Ac = &As_[cur][0];
    const unsigned short* Bc = &Bs_[cur][0];
    #pragma unroll
    for (int kk = 0; kk < 2; ++kk) {
      s8v a[2], b[2];
      int col = (kk * 32 + lg * 8) ^ cswz;
      #pragma unroll
      for (int i = 0; i < 2; ++i)
        a[i] = *(const s8v*)&Ac[(wm + i * 16 + l15) * 64 + col];
      #pragma unroll
      for (int i = 0; i < 2; ++i)
        b[i] = *(const s8v*)&Bc[(wn + i * 16 + l15) * 64 + col];
      __builtin_amdgcn_s_setprio(1);
      #pragma unroll
      for (int mi = 0; mi < 2; ++mi)
        #pragma unroll
        for (int ni = 0; ni < 2; ++ni)
          acc[mi][ni] = __builtin_amdgcn_mfma_f32_16x16x32_bf16(a[mi], b[ni], acc[mi][ni], 0, 0, 0);
      __builtin_amdgcn_s_setprio(0);
    }
    if (tt + 1 < NT) {
      __builtin_amdgcn_sched_barrier(0);
      __builtin_amdgcn_s_barrier();
      __builtin_amdgcn_sched_barrier(0);
    }
  }
  #pragma unroll
  for (int mi = 0; mi < 2; ++mi) {
    #pragma unroll
    for (int ni = 0; ni < 2; ++ni) {
      int col = n0 + wn + ni * 16 + l15;
      float bs = bias[col];
      #pragma unroll
      for (int r = 0; r < 4; ++r) {
        int row = m0 + wm + mi * 16 + lg * 4 + r;
        float v = acc[mi][ni][r] + bs;
        out_f32[(size_t)row * N + col] = resid[(size_t)row * N + col] + v;
      }
    }
  }
}

// ---------------- fused attention: staged K/V + counted vmcnt ---------------
// 768 blocks XCD-chunked; 4 waves x 32 q-cols; LDS 48 KiB -> 3 blocks/CU.
// Q fragments in registers (loaded once, coalesced).  Ps per-wave.
// Per tile: stage(t+1) -> vmcnt(4) -> barrier -> QK^T/softmax/PV -> barrier.
// (Tile t+1's loads stay in flight across the whole compute phase.)
__global__ __launch_bounds__(256, 3) void attn_kernel(
    const unsigned short* __restrict__ qk,  // [8192][768] (q == k, pre-scaled)
    const unsigned short* __restrict__ vt,  // [96][64][1024]
    unsigned short* __restrict__ o)         // [8192][768]
{
  __shared__ __align__(16) unsigned short Ks[2][64 * 64];
  __shared__ __align__(16) unsigned short Vs[2][64 * 64];
  __shared__ __align__(16) unsigned short Ps[4][32 * 64];
  int bid = blockIdx.x;
  int xcd = bid & 7, idx = bid >> 3;
  int bh = xcd * 12 + (idx >> 3), qt = idx & 7;
  int b = bh / 12, h = bh % 12;
  int t = threadIdx.x, lane = t & 63, w = t >> 6;
  int l15 = lane & 15, lg = lane >> 4;
  int wq0 = w << 5;
  size_t qrow0 = (size_t)b * 1024 + qt * 128;
  size_t krow0 = (size_t)b * 1024;
  size_t vbase = ((size_t)bh) * 64 * 1024;
  int cswz = (l15 & 7) << 3;
  unsigned short* myPs = &Ps[w][0];

  int srow = t >> 3;
  int scsw = ((t & 7) << 3) ^ ((srow & 7) << 3);
  const unsigned short* ksrc = &qk[(krow0 + srow) * 768 + h * 64 + scsw];
  const unsigned short* vsrc = &vt[vbase + (size_t)srow * 1024 + scsw];

  auto stage = [&](int buf, int kt) {
    const unsigned short* kp = ksrc + (size_t)kt * 64 * 768;
    const unsigned short* vp = vsrc + kt * 64;
    #pragma unroll
    for (int j = 0; j < 2; ++j) {               // 4 loads/thread
      g2l16(kp + (size_t)j * 32 * 768, &Ks[buf][(j * 256 + w * 64) * 8]);
      g2l16(vp + (size_t)j * 32 * 1024, &Vs[buf][(j * 256 + w * 64) * 8]);
    }
  };

  // Q fragments in registers (reused for all 16 K-tiles)
  s8v qf[2][2];
  #pragma unroll
  for (int ni = 0; ni < 2; ++ni)
    #pragma unroll
    for (int kk = 0; kk < 2; ++kk)
      qf[ni][kk] = *(const s8v*)&qk[(qrow0 + wq0 + ni * 16 + l15) * 768 +
                                    h * 64 + kk * 32 + lg * 8];

  f32x4 oacc[4][2] = {};
  float lsum[2] = {0.f, 0.f};

  stage(0, 0);
  asm volatile("s_waitcnt vmcnt(0)" ::: "memory");
  __builtin_amdgcn_sched_barrier(0);
  __builtin_amdgcn_s_barrier();

  for (int kt = 0; kt < 16; ++kt) {
    int buf = kt & 1;
    if (kt + 1 < 16) {
      stage(buf ^ 1, kt + 1);
      asm volatile("s_waitcnt vmcnt(4)" ::: "memory");
    } else {
      asm volatile("s_waitcnt vmcnt(0)" ::: "memory");
    }
    __builtin_amdgcn_sched_barrier(0);
    __builtin_amdgcn_s_barrier();          // stage(kt) landed block-wide
    __builtin_amdgcn_sched_barrier(0);
    const unsigned short* Kb = Ks[buf];
    const unsigned short* Vb = Vs[buf];
    // S^T = K * Q^T  (pre-scaled into log2 domain)
    f32x4 st[4][2] = {};
    #pragma unroll
    for (int kk = 0; kk < 2; ++kk) {
      int col = (kk * 32 + lg * 8) ^ cswz;
      s8v a[4];
      #pragma unroll
      for (int i = 0; i < 4; ++i) a[i] = *(const s8v*)&Kb[(i * 16 + l15) * 64 + col];
      #pragma unroll
      for (int mi = 0; mi < 4; ++mi)
        #pragma unroll
        for (int ni = 0; ni < 2; ++ni)
          st[mi][ni] = __builtin_amdgcn_mfma_f32_16x16x32_bf16(a[mi], qf[ni][kk], st[mi][ni], 0, 0, 0);
    }
    // P = 2^st -> bf16 pairs -> own-wave Ps rows
    #pragma unroll
    for (int ni = 0; ni < 2; ++ni) {
      int prow = (ni * 16 + l15) * 64;
      #pragma unroll
      for (int mi = 0; mi < 4; ++mi) {
        float p0, p1, p2, p3;
        asm("v_exp_f32 %0, %1" : "=v"(p0) : "v"(st[mi][ni][0]));
        asm("v_exp_f32 %0, %1" : "=v"(p1) : "v"(st[mi][ni][1]));
        asm("v_exp_f32 %0, %1" : "=v"(p2) : "v"(st[mi][ni][2]));
        asm("v_exp_f32 %0, %1" : "=v"(p3) : "v"(st[mi][ni][3]));
        lsum[ni] += (p0 + p1) + (p2 + p3);
        unsigned lo, hi;
        asm("v_cvt_pk_bf16_f32 %0, %1, %2" : "=v"(lo) : "v"(p0), "v"(p1));
        asm("v_cvt_pk_bf16_f32 %0, %1, %2" : "=v"(hi) : "v"(p2), "v"(p3));
        unsigned long long pk = (unsigned long long)lo | ((unsigned long long)hi << 32);
        *(unsigned long long*)&myPs[prow + ((mi * 16 + lg * 4) ^ cswz)] = pk;
      }
    }
    // PV: o^T += V^T * P^T  (own-wave Ps reads; DS pipe in-order per wave)
    #pragma unroll
    for (int kk = 0; kk < 2; ++kk) {
      int col = (kk * 32 + lg * 8) ^ cswz;
      s8v vv[4], bp[2];
      #pragma unroll
      for (int i = 0; i < 4; ++i) vv[i] = *(const s8v*)&Vb[(i * 16 + l15) * 64 + col];
      #pragma unroll
      for (int i = 0; i < 2; ++i) bp[i] = *(const s8v*)&myPs[(i * 16 + l15) * 64 + col];
      #pragma unroll
      for (int ei = 0; ei < 4; ++ei)
        #pragma unroll
        for (int ni = 0; ni < 2; ++ni)
          oacc[ei][ni] = __builtin_amdgcn_mfma_f32_16x16x32_bf16(vv[ei], bp[ni], oacc[ei][ni], 0, 0, 0);
    }
    if (kt + 1 < 16) {
      __builtin_amdgcn_sched_barrier(0);
      __builtin_amdgcn_s_barrier();        // reads of buf done block-wide
      __builtin_amdgcn_sched_barrier(0);
    }
  }
  // finalize: reduce lsum across lg groups, normalize, write o
  #pragma unroll
  for (int ni = 0; ni < 2; ++ni) {
    float s = lsum[ni];
    s += __shfl_xor(s, 16);
    s += __shfl_xor(s, 32);
    float inv = 1.f / s;
    int q = wq0 + ni * 16 + l15;
    size_t obase = (qrow0 + q) * 768 + h * 64;
    #pragma unroll
    for (int ei = 0; ei < 4; ++ei) {
      us4v ov;
      #pragma unroll
      for (int r = 0; r < 4; ++r) ov[r] = f2b(oacc[ei][ni][r] * inv);
      *(us4v*)&o[obase + ei * 16 + lg * 4] = ov;
    }
  }
}

// ---------------------------------------------------------------------------
extern "C" void kernel_launch(void* const* d_in, const int* in_sizes, int n_in,
                              void* d_out, int out_size, void* d_ws, size_t ws_size,
                              hipStream_t stream)
{
  const float* x     = (const float*)d_in[0];
  const float* ln1_g = (const float*)d_in[1];
  const float* ln1_b = (const float*)d_in[2];
  const float* Wq    = (const float*)d_in[3];
  const float* bq    = (const float*)d_in[4];
  const float* Wv    = (const float*)d_in[5];
  const float* bv    = (const float*)d_in[6];
  const float* Wo    = (const float*)d_in[7];
  const float* bo    = (const float*)d_in[8];
  const float* ln2_g = (const float*)d_in[9];
  const float* ln2_b = (const float*)d_in[10];
  const float* W1    = (const float*)d_in[11];
  const float* b1    = (const float*)d_in[12];
  const float* W2    = (const float*)d_in[13];
  const float* b2    = (const float*)d_in[14];
  float* out = (float*)d_out;

  char* ws = (char*)d_ws;
  size_t off = 0;
  auto alloc = [&](size_t bytes) -> void* {
    void* p = ws + off; off += (bytes + 255) & ~(size_t)255; return p;
  };
  unsigned short* Wqv_t  = (unsigned short*)alloc(1536ull * 768 * 2);
  float*          bias_qv= (float*)         alloc(1536ull * 4);
  unsigned short* Wo_t   = (unsigned short*)alloc(768ull * 768 * 2);
  unsigned short* W1_t   = (unsigned short*)alloc(3072ull * 768 * 2);
  unsigned short* W2_t   = (unsigned short*)alloc(768ull * 3072 * 2);
  unsigned short* h_bf   = (unsigned short*)alloc(8192ull * 768 * 2);
  unsigned short* q_bf   = (unsigned short*)alloc(8192ull * 768 * 2);
  unsigned short* v_t    = (unsigned short*)alloc(96ull * 64 * 1024 * 2);
  unsigned short* o_bf   = (unsigned short*)alloc(8192ull * 768 * 2);
  unsigned short* h2_bf  = (unsigned short*)alloc(8192ull * 768 * 2);
  unsigned short* m1_bf  = (unsigned short*)alloc(8192ull * 3072 * 2);

  repack_kernel<<<9216, 256, 0, stream>>>(Wq, bq, Wv, bv, Wo, W1, W2,
                                          Wqv_t, bias_qv, Wo_t, W1_t, W2_t);
  ln_kernel<<<8192, 256, 0, stream>>>(x, ln1_g, ln1_b, h_bf);
  gemm128<3, 1536, 768><<<768, 512, 0, stream>>>(h_bf, Wqv_t, bias_qv,
      nullptr, nullptr, nullptr, q_bf, v_t);
  attn_kernel<<<768, 256, 0, stream>>>(q_bf, v_t, o_bf);
  gemm128<1, 768, 768><<<384, 512, 0, stream>>>(o_bf, Wo_t, bo,
      x, out, nullptr, nullptr, nullptr);
  ln_kernel<<<8192, 256, 0, stream>>>(out, ln2_g, ln2_b, h2_bf);
  gemm128<2, 3072, 768><<<1536, 512, 0, stream>>>(h2_bf, W1_t, b1,
      nullptr, nullptr, m1_bf, nullptr, nullptr);
  gemm_n64<768, 3072><<<768, 512, 0, stream>>>(m1_bf, W2_t, b2, out, out);
}

// Round 18
// 249.118 us; speedup vs baseline: 1.2206x; 1.0091x over previous
//
#include <hip/hip_runtime.h>
#include <stdint.h>

// ---------------------------------------------------------------------------
// Encoder block, MI355X bf16-MFMA (round 18: round-16 base; O-projection moved
// to gemm_n64 (proven FC2 path, EPI=1) -- single-delta isolation after round
// 17's NaN.  QV stays on gemm128<3>.  Quirks: k = q, scale = 768^-0.5.
// ---------------------------------------------------------------------------

typedef __attribute__((ext_vector_type(8))) short s8v;      // 8 x bf16
typedef __attribute__((ext_vector_type(4))) float f32x4;    // MFMA C/D frag
typedef __attribute__((ext_vector_type(4))) unsigned short us4v;

__device__ __forceinline__ unsigned short f2b(float f) {  // f32 -> bf16 RTNE
  union { float f; unsigned u; } v; v.f = f;
  unsigned r = v.u + 0x7FFFu + ((v.u >> 16) & 1u);
  return (unsigned short)(r >> 16);
}

__device__ __forceinline__ void g2l16(const unsigned short* g, unsigned short* l) {
  __builtin_amdgcn_global_load_lds(
      (const __attribute__((address_space(1))) unsigned int*)g,
      (__attribute__((address_space(3))) unsigned int*)l, 16, 0, 0);
}

// sqrt(768^-0.5 * log2(e)): folded into BOTH q and k (same tensor, k=q quirk)
#define QSCALE 0.22816534f

// ---------------- weight repack: all weights -> bf16, B^T [N][K] layout ------
__global__ __launch_bounds__(256) void repack_kernel(
    const float* __restrict__ Wq, const float* __restrict__ bq,
    const float* __restrict__ Wv, const float* __restrict__ bv,
    const float* __restrict__ Wo, const float* __restrict__ W1,
    const float* __restrict__ W2,
    unsigned short* __restrict__ Wqv_t, float* __restrict__ bias_qv,
    unsigned short* __restrict__ Wo_t, unsigned short* __restrict__ W1_t,
    unsigned short* __restrict__ W2_t)
{
  int i = blockIdx.x * 256 + threadIdx.x;
  if (i < 1536 * 768) {
    int n = i / 768, d = i % 768;
    float val;
    if (n < 768) { int h = n >> 6, e = n & 63; val = Wq[(h * 768 + d) * 64 + e] * QSCALE; }
    else { int c = n - 768; int h = c >> 6, e = c & 63; val = Wv[(h * 768 + d) * 64 + e]; }
    Wqv_t[i] = f2b(val);
  }
  if (i < 1536) bias_qv[i] = (i < 768) ? bq[i] * QSCALE : bv[i - 768];
  if (i < 768 * 768)  { int n = i / 768,  k = i % 768;  Wo_t[i] = f2b(Wo[k * 768  + n]); }
  if (i < 3072 * 768) { int n = i / 768,  k = i % 768;  W1_t[i] = f2b(W1[k * 3072 + n]); }
  if (i < 768 * 3072) { int n = i / 3072, k = i % 3072; W2_t[i] = f2b(W2[k * 768  + n]); }
}

// ---------------- LayerNorm: f32 [8192][768] -> bf16 ------------------------
__global__ __launch_bounds__(256) void ln_kernel(
    const float* __restrict__ x, const float* __restrict__ g,
    const float* __restrict__ b, unsigned short* __restrict__ out)
{
  __shared__ float red[4], red2[4];
  int row = blockIdx.x, t = threadIdx.x;
  const float* xr = x + (size_t)row * 768;
  float v0 = xr[t], v1 = xr[t + 256], v2 = xr[t + 512];
  float s = v0 + v1 + v2;
  #pragma unroll
  for (int m = 32; m; m >>= 1) s += __shfl_xor(s, m);
  if ((t & 63) == 0) red[t >> 6] = s;
  __syncthreads();
  float mean = (red[0] + red[1] + red[2] + red[3]) * (1.f / 768.f);
  float d0 = v0 - mean, d1 = v1 - mean, d2 = v2 - mean;
  float vs = d0 * d0 + d1 * d1 + d2 * d2;
  #pragma unroll
  for (int m = 32; m; m >>= 1) vs += __shfl_xor(vs, m);
  if ((t & 63) == 0) red2[t >> 6] = vs;
  __syncthreads();
  float var = (red2[0] + red2[1] + red2[2] + red2[3]) * (1.f / 768.f);
  float rs = rsqrtf(var + 1e-5f);
  unsigned short* o = out + (size_t)row * 768;
  o[t]       = f2b(d0 * rs * g[t]       + b[t]);
  o[t + 256] = f2b(d1 * rs * g[t + 256] + b[t + 256]);
  o[t + 512] = f2b(d2 * rs * g[t + 512] + b[t + 512]);
}

// banded within-chunk map: bands of BAND m-tiles, n swept per band, m fastest
template<int NTN, int BAND>
__device__ __forceinline__ void band_map(int bid, int grid, int& m_t, int& n_t) {
  int q8 = grid >> 3;
  int mb = q8 / NTN;
  int xcd = bid & 7, idx = bid >> 3;
  int pb = BAND * NTN;
  int band = idx / pb, r = idx % pb;
  m_t = xcd * mb + band * BAND + (r % BAND);
  n_t = r / BAND;
}

// shared epilogue: EPI 1 = f32 resid+acc+bias; 2 = bf16 tanh-gelu; 3 = qv split
template<int EPI, int N>
__device__ __forceinline__ void epi_write(
    float v, int row, int col,
    const float* resid, float* out_f32, unsigned short* out_bf,
    unsigned short* q_out, unsigned short* vt_out)
{
  if (EPI == 1) {
    out_f32[(size_t)row * N + col] = resid[(size_t)row * N + col] + v;
  } else if (EPI == 2) {
    // tanh-gelu via exp2: v * sigmoid(1.5957688(v + 0.044715 v^3))
    float v2 = v * v;
    float z = v * fmaf(-0.10294202f, v2, -2.302026f);
    float e; asm("v_exp_f32 %0, %1" : "=v"(e) : "v"(z));
    float rcp; asm("v_rcp_f32 %0, %1" : "=v"(rcp) : "v"(e + 1.0f));
    out_bf[(size_t)row * N + col] = f2b(v * rcp);
  } else { // EPI == 3
    if (col < 768) {
      q_out[(size_t)row * 768 + col] = f2b(v);
    } else {
      int c = col - 768; int hh = c >> 6, e = c & 63;
      int bb = row >> 10, s = row & 1023;
      vt_out[(((size_t)(bb * 12 + hh)) * 64 + e) * 1024 + s] = f2b(v);
    }
  }
}

// ---------------- 8-wave 128x128 2-buf counted-vmcnt GEMM (QV, FC1) ----------
template<int EPI, int N, int K>
__global__ __launch_bounds__(512, 4) void gemm128(
    const unsigned short* __restrict__ A, const unsigned short* __restrict__ Bt,
    const float* __restrict__ bias,
    const float* resid, float* out_f32,
    unsigned short* __restrict__ out_bf,
    unsigned short* __restrict__ q_out, unsigned short* __restrict__ vt_out)
{
  __shared__ __align__(16) unsigned short As_[2][8192];
  __shared__ __align__(16) unsigned short Bs_[2][8192];
  constexpr int NTN = N >> 7;
  constexpr int NT = K >> 6;
  int m_t, n_t;
  band_map<NTN, 4>(blockIdx.x, gridDim.x, m_t, n_t);
  int m0 = m_t << 7, n0 = n_t << 7;
  int t = threadIdx.x, lane = t & 63, w = t >> 6;  // w 0..7
  int l15 = lane & 15, lg = lane >> 4;
  int wm = (w >> 2) << 6;                       // 0 / 64
  int wn = (w & 3) << 5;                        // 0 / 32 / 64 / 96
  int lrow = lane >> 3;                         // 0..7
  int lxor = ((lane & 7) ^ lrow) << 3;          // pre-swizzled src col (ushort)
  const unsigned short* Abase = A + (size_t)m0 * K;
  const unsigned short* Bbase = Bt + (size_t)n0 * K;

  auto stage = [&](int buf, int tile) {
    int k0 = tile << 6;
    #pragma unroll
    for (int j = 0; j < 2; ++j) {               // 4 loads/thread: A,B x j
      int row = j * 64 + w * 8 + lrow;
      int doff = (j * 512 + w * 64) * 8;        // wave-uniform dest (ushort)
      g2l16(&Abase[(size_t)row * K + k0 + lxor], &As_[buf][doff]);
      g2l16(&Bbase[(size_t)row * K + k0 + lxor], &Bs_[buf][doff]);
    }
  };

  f32x4 acc[4][2] = {};
  stage(0, 0);
  asm volatile("s_waitcnt vmcnt(0)" ::: "memory");
  __builtin_amdgcn_sched_barrier(0);
  __builtin_amdgcn_s_barrier();

  int cswz = (l15 & 7) << 3;
  for (int tt = 0; tt < NT; ++tt) {
    int cur = tt & 1;
    if (tt + 1 < NT) {
      stage(cur ^ 1, tt + 1);
      asm volatile("s_waitcnt vmcnt(4)" ::: "memory");
    } else {
      asm volatile("s_waitcnt vmcnt(0)" ::: "memory");
    }
    __builtin_amdgcn_sched_barrier(0);
    __builtin_amdgcn_s_barrier();          // all waves' stage(tt) landed
    __builtin_amdgcn_sched_barrier(0);
    const unsigned short* Ac = &As_[cur][0];
    const unsigned short* Bc = &Bs_[cur][0];
    #pragma unroll
    for (int kk = 0; kk < 2; ++kk) {
      s8v a[4], b[2];
      int col = (kk * 32 + lg * 8) ^ cswz;
      #pragma unroll
      for (int i = 0; i < 4; ++i)
        a[i] = *(const s8v*)&Ac[(wm + i * 16 + l15) * 64 + col];
      #pragma unroll
      for (int i = 0; i < 2; ++i)
        b[i] = *(const s8v*)&Bc[(wn + i * 16 + l15) * 64 + col];
      __builtin_amdgcn_s_setprio(1);
      #pragma unroll
      for (int mi = 0; mi < 4; ++mi)
        #pragma unroll
        for (int ni = 0; ni < 2; ++ni)
          acc[mi][ni] = __builtin_amdgcn_mfma_f32_16x16x32_bf16(a[mi], b[ni], acc[mi][ni], 0, 0, 0);
      __builtin_amdgcn_s_setprio(0);
    }
    if (tt + 1 < NT) {
      __builtin_amdgcn_sched_barrier(0);
      __builtin_amdgcn_s_barrier();        // reads of buf cur done block-wide
      __builtin_amdgcn_sched_barrier(0);
    }
  }
  #pragma unroll
  for (int mi = 0; mi < 4; ++mi)
    #pragma unroll
    for (int ni = 0; ni < 2; ++ni) {
      int col = n0 + wn + ni * 16 + l15;
      float bs = bias[col];
      #pragma unroll
      for (int r = 0; r < 4; ++r)
        epi_write<EPI, N>(acc[mi][ni][r] + bs, m0 + wm + mi * 16 + lg * 4 + r,
                          col, resid, out_f32, out_bf, q_out, vt_out);
    }
}

// ---------------- 128x64 tile, 8 waves, 3 blocks/CU (O, FC2) -----------------
// EPI=1 only (proven path): f32 out = resid + acc + bias.  Counted vmcnt(3).
template<int N, int K>
__global__ __launch_bounds__(512, 6) void gemm_n64(
    const unsigned short* __restrict__ A, const unsigned short* __restrict__ Bt,
    const float* __restrict__ bias, const float* resid, float* out_f32)
{
  __shared__ __align__(16) unsigned short As_[2][8192];   // 128x64
  __shared__ __align__(16) unsigned short Bs_[2][4096];   // 64x64
  constexpr int NTN = N >> 6;
  constexpr int NT = K >> 6;
  int m_t, n_t;
  band_map<NTN, 4>(blockIdx.x, gridDim.x, m_t, n_t);
  int m0 = m_t << 7, n0 = n_t << 6;
  int t = threadIdx.x, lane = t & 63, w = t >> 6;
  int l15 = lane & 15, lg = lane >> 4;
  int wm = (w >> 1) << 5;                       // 0/32/64/96
  int wn = (w & 1) << 5;                        // 0/32
  int lrow = lane >> 3;
  int lxor = ((lane & 7) ^ lrow) << 3;
  const unsigned short* Abase = A + (size_t)m0 * K;
  const unsigned short* Bbase = Bt + (size_t)n0 * K;

  auto stage = [&](int buf, int tile) {
    int k0 = tile << 6;
    #pragma unroll
    for (int j = 0; j < 2; ++j) {               // A: 2 loads/thread
      int row = j * 64 + w * 8 + lrow;
      g2l16(&Abase[(size_t)row * K + k0 + lxor], &As_[buf][(j * 512 + w * 64) * 8]);
    }
    int brow = w * 8 + lrow;                    // B: 1 load/thread
    g2l16(&Bbase[(size_t)brow * K + k0 + lxor], &Bs_[buf][w * 512]);
  };

  f32x4 acc[2][2] = {};
  stage(0, 0);
  asm volatile("s_waitcnt vmcnt(0)" ::: "memory");
  __builtin_amdgcn_sched_barrier(0);
  __builtin_amdgcn_s_barrier();

  int cswz = (l15 & 7) << 3;
  for (int tt = 0; tt < NT; ++tt) {
    int cur = tt & 1;
    if (tt + 1 < NT) {
      stage(cur ^ 1, tt + 1);
      asm volatile("s_waitcnt vmcnt(3)" ::: "memory");
    } else {
      asm volatile("s_waitcnt vmcnt(0)" ::: "memory");
    }
    __builtin_amdgcn_sched_barrier(0);
    __builtin_amdgcn_s_barrier();
    __builtin_amdgcn_sched_barrier(0);
    const unsigned short* Ac = &As_[cur][0];
    const unsigned short* Bc = &Bs_[cur][0];
    #pragma unroll
    for (int kk = 0; kk < 2; ++kk) {
      s8v a[2], b[2];
      int col = (kk * 32 + lg * 8) ^ cswz;
      #pragma unroll
      for (int i = 0; i < 2; ++i)
        a[i] = *(const s8v*)&Ac[(wm + i * 16 + l15) * 64 + col];
      #pragma unroll
      for (int i = 0; i < 2; ++i)
        b[i] = *(const s8v*)&Bc[(wn + i * 16 + l15) * 64 + col];
      __builtin_amdgcn_s_setprio(1);
      #pragma unroll
      for (int mi = 0; mi < 2; ++mi)
        #pragma unroll
        for (int ni = 0; ni < 2; ++ni)
          acc[mi][ni] = __builtin_amdgcn_mfma_f32_16x16x32_bf16(a[mi], b[ni], acc[mi][ni], 0, 0, 0);
      __builtin_amdgcn_s_setprio(0);
    }
    if (tt + 1 < NT) {
      __builtin_amdgcn_sched_barrier(0);
      __builtin_amdgcn_s_barrier();
      __builtin_amdgcn_sched_barrier(0);
    }
  }
  #pragma unroll
  for (int mi = 0; mi < 2; ++mi) {
    #pragma unroll
    for (int ni = 0; ni < 2; ++ni) {
      int col = n0 + wn + ni * 16 + l15;
      float bs = bias[col];
      #pragma unroll
      for (int r = 0; r < 4; ++r) {
        int row = m0 + wm + mi * 16 + lg * 4 + r;
        float v = acc[mi][ni][r] + bs;
        out_f32[(size_t)row * N + col] = resid[(size_t)row * N + col] + v;
      }
    }
  }
}

// ---------------- fused attention: staged K/V + counted vmcnt ---------------
// 768 blocks XCD-chunked; 4 waves x 32 q-cols; LDS 48 KiB -> 3 blocks/CU.
// Q in registers; per-wave Ps; stage(t+1) -> vmcnt(4) -> barrier -> compute.
__global__ __launch_bounds__(256, 3) void attn_kernel(
    const unsigned short* __restrict__ qk,  // [8192][768] (q == k, pre-scaled)
    const unsigned short* __restrict__ vt,  // [96][64][1024]
    unsigned short* __restrict__ o)         // [8192][768]
{
  __shared__ __align__(16) unsigned short Ks[2][64 * 64];
  __shared__ __align__(16) unsigned short Vs[2][64 * 64];
  __shared__ __align__(16) unsigned short Ps[4][32 * 64];
  int bid = blockIdx.x;
  int xcd = bid & 7, idx = bid >> 3;
  int bh = xcd * 12 + (idx >> 3), qt = idx & 7;
  int b = bh / 12, h = bh % 12;
  int t = threadIdx.x, lane = t & 63, w = t >> 6;
  int l15 = lane & 15, lg = lane >> 4;
  int wq0 = w << 5;
  size_t qrow0 = (size_t)b * 1024 + qt * 128;
  size_t krow0 = (size_t)b * 1024;
  size_t vbase = ((size_t)bh) * 64 * 1024;
  int cswz = (l15 & 7) << 3;
  unsigned short* myPs = &Ps[w][0];

  int srow = t >> 3;
  int scsw = ((t & 7) << 3) ^ ((srow & 7) << 3);
  const unsigned short* ksrc = &qk[(krow0 + srow) * 768 + h * 64 + scsw];
  const unsigned short* vsrc = &vt[vbase + (size_t)srow * 1024 + scsw];

  auto stage = [&](int buf, int kt) {
    const unsigned short* kp = ksrc + (size_t)kt * 64 * 768;
    const unsigned short* vp = vsrc + kt * 64;
    #pragma unroll
    for (int j = 0; j < 2; ++j) {               // 4 loads/thread
      g2l16(kp + (size_t)j * 32 * 768, &Ks[buf][(j * 256 + w * 64) * 8]);
      g2l16(vp + (size_t)j * 32 * 1024, &Vs[buf][(j * 256 + w * 64) * 8]);
    }
  };

  // Q fragments in registers (reused for all 16 K-tiles)
  s8v qf[2][2];
  #pragma unroll
  for (int ni = 0; ni < 2; ++ni)
    #pragma unroll
    for (int kk = 0; kk < 2; ++kk)
      qf[ni][kk] = *(const s8v*)&qk[(qrow0 + wq0 + ni * 16 + l15) * 768 +
                                    h * 64 + kk * 32 + lg * 8];

  f32x4 oacc[4][2] = {};
  float lsum[2] = {0.f, 0.f};

  stage(0, 0);
  asm volatile("s_waitcnt vmcnt(0)" ::: "memory");
  __builtin_amdgcn_sched_barrier(0);
  __builtin_amdgcn_s_barrier();

  for (int kt = 0; kt < 16; ++kt) {
    int buf = kt & 1;
    if (kt + 1 < 16) {
      stage(buf ^ 1, kt + 1);
      asm volatile("s_waitcnt vmcnt(4)" ::: "memory");
    } else {
      asm volatile("s_waitcnt vmcnt(0)" ::: "memory");
    }
    __builtin_amdgcn_sched_barrier(0);
    __builtin_amdgcn_s_barrier();          // stage(kt) landed block-wide
    __builtin_amdgcn_sched_barrier(0);
    const unsigned short* Kb = Ks[buf];
    const unsigned short* Vb = Vs[buf];
    f32x4 st[4][2] = {};
    #pragma unroll
    for (int kk = 0; kk < 2; ++kk) {
      int col = (kk * 32 + lg * 8) ^ cswz;
      s8v a[4];
      #pragma unroll
      for (int i = 0; i < 4; ++i) a[i] = *(const s8v*)&Kb[(i * 16 + l15) * 64 + col];
      #pragma unroll
      for (int mi = 0; mi < 4; ++mi)
        #pragma unroll
        for (int ni = 0; ni < 2; ++ni)
          st[mi][ni] = __builtin_amdgcn_mfma_f32_16x16x32_bf16(a[mi], qf[ni][kk], st[mi][ni], 0, 0, 0);
    }
    #pragma unroll
    for (int ni = 0; ni < 2; ++ni) {
      int prow = (ni * 16 + l15) * 64;
      #pragma unroll
      for (int mi = 0; mi < 4; ++mi) {
        float p0, p1, p2, p3;
        asm("v_exp_f32 %0, %1" : "=v"(p0) : "v"(st[mi][ni][0]));
        asm("v_exp_f32 %0, %1" : "=v"(p1) : "v"(st[mi][ni][1]));
        asm("v_exp_f32 %0, %1" : "=v"(p2) : "v"(st[mi][ni][2]));
        asm("v_exp_f32 %0, %1" : "=v"(p3) : "v"(st[mi][ni][3]));
        lsum[ni] += (p0 + p1) + (p2 + p3);
        unsigned lo, hi;
        asm("v_cvt_pk_bf16_f32 %0, %1, %2" : "=v"(lo) : "v"(p0), "v"(p1));
        asm("v_cvt_pk_bf16_f32 %0, %1, %2" : "=v"(hi) : "v"(p2), "v"(p3));
        unsigned long long pk = (unsigned long long)lo | ((unsigned long long)hi << 32);
        *(unsigned long long*)&myPs[prow + ((mi * 16 + lg * 4) ^ cswz)] = pk;
      }
    }
    #pragma unroll
    for (int kk = 0; kk < 2; ++kk) {
      int col = (kk * 32 + lg * 8) ^ cswz;
      s8v vv[4], bp[2];
      #pragma unroll
      for (int i = 0; i < 4; ++i) vv[i] = *(const s8v*)&Vb[(i * 16 + l15) * 64 + col];
      #pragma unroll
      for (int i = 0; i < 2; ++i) bp[i] = *(const s8v*)&myPs[(i * 16 + l15) * 64 + col];
      #pragma unroll
      for (int ei = 0; ei < 4; ++ei)
        #pragma unroll
        for (int ni = 0; ni < 2; ++ni)
          oacc[ei][ni] = __builtin_amdgcn_mfma_f32_16x16x32_bf16(vv[ei], bp[ni], oacc[ei][ni], 0, 0, 0);
    }
    if (kt + 1 < 16) {
      __builtin_amdgcn_sched_barrier(0);
      __builtin_amdgcn_s_barrier();        // reads of buf done block-wide
      __builtin_amdgcn_sched_barrier(0);
    }
  }
  #pragma unroll
  for (int ni = 0; ni < 2; ++ni) {
    float s = lsum[ni];
    s += __shfl_xor(s, 16);
    s += __shfl_xor(s, 32);
    float inv = 1.f / s;
    int q = wq0 + ni * 16 + l15;
    size_t obase = (qrow0 + q) * 768 + h * 64;
    #pragma unroll
    for (int ei = 0; ei < 4; ++ei) {
      us4v ov;
      #pragma unroll
      for (int r = 0; r < 4; ++r) ov[r] = f2b(oacc[ei][ni][r] * inv);
      *(us4v*)&o[obase + ei * 16 + lg * 4] = ov;
    }
  }
}

// ---------------------------------------------------------------------------
extern "C" void kernel_launch(void* const* d_in, const int* in_sizes, int n_in,
                              void* d_out, int out_size, void* d_ws, size_t ws_size,
                              hipStream_t stream)
{
  const float* x     = (const float*)d_in[0];
  const float* ln1_g = (const float*)d_in[1];
  const float* ln1_b = (const float*)d_in[2];
  const float* Wq    = (const float*)d_in[3];
  const float* bq    = (const float*)d_in[4];
  const float* Wv    = (const float*)d_in[5];
  const float* bv    = (const float*)d_in[6];
  const float* Wo    = (const float*)d_in[7];
  const float* bo    = (const float*)d_in[8];
  const float* ln2_g = (const float*)d_in[9];
  const float* ln2_b = (const float*)d_in[10];
  const float* W1    = (const float*)d_in[11];
  const float* b1    = (const float*)d_in[12];
  const float* W2    = (const float*)d_in[13];
  const float* b2    = (const float*)d_in[14];
  float* out = (float*)d_out;

  char* ws = (char*)d_ws;
  size_t off = 0;
  auto alloc = [&](size_t bytes) -> void* {
    void* p = ws + off; off += (bytes + 255) & ~(size_t)255; return p;
  };
  unsigned short* Wqv_t  = (unsigned short*)alloc(1536ull * 768 * 2);
  float*          bias_qv= (float*)         alloc(1536ull * 4);
  unsigned short* Wo_t   = (unsigned short*)alloc(768ull * 768 * 2);
  unsigned short* W1_t   = (unsigned short*)alloc(3072ull * 768 * 2);
  unsigned short* W2_t   = (unsigned short*)alloc(768ull * 3072 * 2);
  unsigned short* h_bf   = (unsigned short*)alloc(8192ull * 768 * 2);
  unsigned short* q_bf   = (unsigned short*)alloc(8192ull * 768 * 2);
  unsigned short* v_t    = (unsigned short*)alloc(96ull * 64 * 1024 * 2);
  unsigned short* o_bf   = (unsigned short*)alloc(8192ull * 768 * 2);
  unsigned short* h2_bf  = (unsigned short*)alloc(8192ull * 768 * 2);
  unsigned short* m1_bf  = (unsigned short*)alloc(8192ull * 3072 * 2);

  repack_kernel<<<9216, 256, 0, stream>>>(Wq, bq, Wv, bv, Wo, W1, W2,
                                          Wqv_t, bias_qv, Wo_t, W1_t, W2_t);
  ln_kernel<<<8192, 256, 0, stream>>>(x, ln1_g, ln1_b, h_bf);
  gemm128<3, 1536, 768><<<768, 512, 0, stream>>>(h_bf, Wqv_t, bias_qv,
      nullptr, nullptr, nullptr, q_bf, v_t);
  attn_kernel<<<768, 256, 0, stream>>>(q_bf, v_t, o_bf);
  gemm_n64<768, 768><<<768, 512, 0, stream>>>(o_bf, Wo_t, bo, x, out);
  ln_kernel<<<8192, 256, 0, stream>>>(out, ln2_g, ln2_b, h2_bf);
  gemm128<2, 3072, 768><<<1536, 512, 0, stream>>>(h2_bf, W1_t, b1,
      nullptr, nullptr, m1_bf, nullptr, nullptr);
  gemm_n64<768, 3072><<<768, 512, 0, stream>>>(m1_bf, W2_t, b2, out, out);
}

// Round 19
// 248.502 us; speedup vs baseline: 1.2236x; 1.0025x over previous
//
#include <hip/hip_runtime.h>
#include <stdint.h>

// ---------------------------------------------------------------------------
// Encoder block, MI355X bf16-MFMA (round 19: round-18 base + repack/LN1 fused
// into one prep kernel -- overlapping the two independent memory-bound
// streams; one fewer launch).  Quirks: k = q, scale = 768^-0.5.
// ---------------------------------------------------------------------------

typedef __attribute__((ext_vector_type(8))) short s8v;      // 8 x bf16
typedef __attribute__((ext_vector_type(4))) float f32x4;    // MFMA C/D frag
typedef __attribute__((ext_vector_type(4))) unsigned short us4v;

__device__ __forceinline__ unsigned short f2b(float f) {  // f32 -> bf16 RTNE
  union { float f; unsigned u; } v; v.f = f;
  unsigned r = v.u + 0x7FFFu + ((v.u >> 16) & 1u);
  return (unsigned short)(r >> 16);
}

__device__ __forceinline__ void g2l16(const unsigned short* g, unsigned short* l) {
  __builtin_amdgcn_global_load_lds(
      (const __attribute__((address_space(1))) unsigned int*)g,
      (__attribute__((address_space(3))) unsigned int*)l, 16, 0, 0);
}

// sqrt(768^-0.5 * log2(e)): folded into BOTH q and k (same tensor, k=q quirk)
#define QSCALE 0.22816534f

// ---------------- fused prep: weight repack (blocks 0..9215) +
//                  LayerNorm1 (blocks 9216..17407) ---------------------------
__global__ __launch_bounds__(256) void prep_kernel(
    const float* __restrict__ Wq, const float* __restrict__ bq,
    const float* __restrict__ Wv, const float* __restrict__ bv,
    const float* __restrict__ Wo, const float* __restrict__ W1,
    const float* __restrict__ W2,
    unsigned short* __restrict__ Wqv_t, float* __restrict__ bias_qv,
    unsigned short* __restrict__ Wo_t, unsigned short* __restrict__ W1_t,
    unsigned short* __restrict__ W2_t,
    const float* __restrict__ x, const float* __restrict__ ln1_g,
    const float* __restrict__ ln1_b, unsigned short* __restrict__ h_out)
{
  int bid = blockIdx.x, t = threadIdx.x;
  if (bid < 9216) {
    // ---- repack ----
    int i = bid * 256 + t;
    if (i < 1536 * 768) {
      int n = i / 768, d = i % 768;
      float val;
      if (n < 768) { int h = n >> 6, e = n & 63; val = Wq[(h * 768 + d) * 64 + e] * QSCALE; }
      else { int c = n - 768; int h = c >> 6, e = c & 63; val = Wv[(h * 768 + d) * 64 + e]; }
      Wqv_t[i] = f2b(val);
    }
    if (i < 1536) bias_qv[i] = (i < 768) ? bq[i] * QSCALE : bv[i - 768];
    if (i < 768 * 768)  { int n = i / 768,  k = i % 768;  Wo_t[i] = f2b(Wo[k * 768  + n]); }
    if (i < 3072 * 768) { int n = i / 768,  k = i % 768;  W1_t[i] = f2b(W1[k * 3072 + n]); }
    if (i < 768 * 3072) { int n = i / 3072, k = i % 3072; W2_t[i] = f2b(W2[k * 768  + n]); }
    return;
  }
  // ---- LayerNorm1 ----
  __shared__ float red[4], red2[4];
  int row = bid - 9216;
  const float* xr = x + (size_t)row * 768;
  float v0 = xr[t], v1 = xr[t + 256], v2 = xr[t + 512];
  float s = v0 + v1 + v2;
  #pragma unroll
  for (int m = 32; m; m >>= 1) s += __shfl_xor(s, m);
  if ((t & 63) == 0) red[t >> 6] = s;
  __syncthreads();
  float mean = (red[0] + red[1] + red[2] + red[3]) * (1.f / 768.f);
  float d0 = v0 - mean, d1 = v1 - mean, d2 = v2 - mean;
  float vs = d0 * d0 + d1 * d1 + d2 * d2;
  #pragma unroll
  for (int m = 32; m; m >>= 1) vs += __shfl_xor(vs, m);
  if ((t & 63) == 0) red2[t >> 6] = vs;
  __syncthreads();
  float var = (red2[0] + red2[1] + red2[2] + red2[3]) * (1.f / 768.f);
  float rs = rsqrtf(var + 1e-5f);
  unsigned short* o = h_out + (size_t)row * 768;
  o[t]       = f2b(d0 * rs * ln1_g[t]       + ln1_b[t]);
  o[t + 256] = f2b(d1 * rs * ln1_g[t + 256] + ln1_b[t + 256]);
  o[t + 512] = f2b(d2 * rs * ln1_g[t + 512] + ln1_b[t + 512]);
}

// ---------------- LayerNorm (LN2): f32 [8192][768] -> bf16 -------------------
__global__ __launch_bounds__(256) void ln_kernel(
    const float* __restrict__ x, const float* __restrict__ g,
    const float* __restrict__ b, unsigned short* __restrict__ out)
{
  __shared__ float red[4], red2[4];
  int row = blockIdx.x, t = threadIdx.x;
  const float* xr = x + (size_t)row * 768;
  float v0 = xr[t], v1 = xr[t + 256], v2 = xr[t + 512];
  float s = v0 + v1 + v2;
  #pragma unroll
  for (int m = 32; m; m >>= 1) s += __shfl_xor(s, m);
  if ((t & 63) == 0) red[t >> 6] = s;
  __syncthreads();
  float mean = (red[0] + red[1] + red[2] + red[3]) * (1.f / 768.f);
  float d0 = v0 - mean, d1 = v1 - mean, d2 = v2 - mean;
  float vs = d0 * d0 + d1 * d1 + d2 * d2;
  #pragma unroll
  for (int m = 32; m; m >>= 1) vs += __shfl_xor(vs, m);
  if ((t & 63) == 0) red2[t >> 6] = vs;
  __syncthreads();
  float var = (red2[0] + red2[1] + red2[2] + red2[3]) * (1.f / 768.f);
  float rs = rsqrtf(var + 1e-5f);
  unsigned short* o = out + (size_t)row * 768;
  o[t]       = f2b(d0 * rs * g[t]       + b[t]);
  o[t + 256] = f2b(d1 * rs * g[t + 256] + b[t + 256]);
  o[t + 512] = f2b(d2 * rs * g[t + 512] + b[t + 512]);
}

// banded within-chunk map: bands of BAND m-tiles, n swept per band, m fastest
template<int NTN, int BAND>
__device__ __forceinline__ void band_map(int bid, int grid, int& m_t, int& n_t) {
  int q8 = grid >> 3;
  int mb = q8 / NTN;
  int xcd = bid & 7, idx = bid >> 3;
  int pb = BAND * NTN;
  int band = idx / pb, r = idx % pb;
  m_t = xcd * mb + band * BAND + (r % BAND);
  n_t = r / BAND;
}

// shared epilogue: EPI 1 = f32 resid+acc+bias; 2 = bf16 tanh-gelu; 3 = qv split
template<int EPI, int N>
__device__ __forceinline__ void epi_write(
    float v, int row, int col,
    const float* resid, float* out_f32, unsigned short* out_bf,
    unsigned short* q_out, unsigned short* vt_out)
{
  if (EPI == 1) {
    out_f32[(size_t)row * N + col] = resid[(size_t)row * N + col] + v;
  } else if (EPI == 2) {
    // tanh-gelu via exp2: v * sigmoid(1.5957688(v + 0.044715 v^3))
    float v2 = v * v;
    float z = v * fmaf(-0.10294202f, v2, -2.302026f);
    float e; asm("v_exp_f32 %0, %1" : "=v"(e) : "v"(z));
    float rcp; asm("v_rcp_f32 %0, %1" : "=v"(rcp) : "v"(e + 1.0f));
    out_bf[(size_t)row * N + col] = f2b(v * rcp);
  } else { // EPI == 3
    if (col < 768) {
      q_out[(size_t)row * 768 + col] = f2b(v);
    } else {
      int c = col - 768; int hh = c >> 6, e = c & 63;
      int bb = row >> 10, s = row & 1023;
      vt_out[(((size_t)(bb * 12 + hh)) * 64 + e) * 1024 + s] = f2b(v);
    }
  }
}

// ---------------- 8-wave 128x128 2-buf counted-vmcnt GEMM (QV, FC1) ----------
template<int EPI, int N, int K>
__global__ __launch_bounds__(512, 4) void gemm128(
    const unsigned short* __restrict__ A, const unsigned short* __restrict__ Bt,
    const float* __restrict__ bias,
    const float* resid, float* out_f32,
    unsigned short* __restrict__ out_bf,
    unsigned short* __restrict__ q_out, unsigned short* __restrict__ vt_out)
{
  __shared__ __align__(16) unsigned short As_[2][8192];
  __shared__ __align__(16) unsigned short Bs_[2][8192];
  constexpr int NTN = N >> 7;
  constexpr int NT = K >> 6;
  int m_t, n_t;
  band_map<NTN, 4>(blockIdx.x, gridDim.x, m_t, n_t);
  int m0 = m_t << 7, n0 = n_t << 7;
  int t = threadIdx.x, lane = t & 63, w = t >> 6;  // w 0..7
  int l15 = lane & 15, lg = lane >> 4;
  int wm = (w >> 2) << 6;                       // 0 / 64
  int wn = (w & 3) << 5;                        // 0 / 32 / 64 / 96
  int lrow = lane >> 3;                         // 0..7
  int lxor = ((lane & 7) ^ lrow) << 3;          // pre-swizzled src col (ushort)
  const unsigned short* Abase = A + (size_t)m0 * K;
  const unsigned short* Bbase = Bt + (size_t)n0 * K;

  auto stage = [&](int buf, int tile) {
    int k0 = tile << 6;
    #pragma unroll
    for (int j = 0; j < 2; ++j) {               // 4 loads/thread: A,B x j
      int row = j * 64 + w * 8 + lrow;
      int doff = (j * 512 + w * 64) * 8;        // wave-uniform dest (ushort)
      g2l16(&Abase[(size_t)row * K + k0 + lxor], &As_[buf][doff]);
      g2l16(&Bbase[(size_t)row * K + k0 + lxor], &Bs_[buf][doff]);
    }
  };

  f32x4 acc[4][2] = {};
  stage(0, 0);
  asm volatile("s_waitcnt vmcnt(0)" ::: "memory");
  __builtin_amdgcn_sched_barrier(0);
  __builtin_amdgcn_s_barrier();

  int cswz = (l15 & 7) << 3;
  for (int tt = 0; tt < NT; ++tt) {
    int cur = tt & 1;
    if (tt + 1 < NT) {
      stage(cur ^ 1, tt + 1);
      asm volatile("s_waitcnt vmcnt(4)" ::: "memory");
    } else {
      asm volatile("s_waitcnt vmcnt(0)" ::: "memory");
    }
    __builtin_amdgcn_sched_barrier(0);
    __builtin_amdgcn_s_barrier();          // all waves' stage(tt) landed
    __builtin_amdgcn_sched_barrier(0);
    const unsigned short* Ac = &As_[cur][0];
    const unsigned short* Bc = &Bs_[cur][0];
    #pragma unroll
    for (int kk = 0; kk < 2; ++kk) {
      s8v a[4], b[2];
      int col = (kk * 32 + lg * 8) ^ cswz;
      #pragma unroll
      for (int i = 0; i < 4; ++i)
        a[i] = *(const s8v*)&Ac[(wm + i * 16 + l15) * 64 + col];
      #pragma unroll
      for (int i = 0; i < 2; ++i)
        b[i] = *(const s8v*)&Bc[(wn + i * 16 + l15) * 64 + col];
      __builtin_amdgcn_s_setprio(1);
      #pragma unroll
      for (int mi = 0; mi < 4; ++mi)
        #pragma unroll
        for (int ni = 0; ni < 2; ++ni)
          acc[mi][ni] = __builtin_amdgcn_mfma_f32_16x16x32_bf16(a[mi], b[ni], acc[mi][ni], 0, 0, 0);
      __builtin_amdgcn_s_setprio(0);
    }
    if (tt + 1 < NT) {
      __builtin_amdgcn_sched_barrier(0);
      __builtin_amdgcn_s_barrier();        // reads of buf cur done block-wide
      __builtin_amdgcn_sched_barrier(0);
    }
  }
  #pragma unroll
  for (int mi = 0; mi < 4; ++mi)
    #pragma unroll
    for (int ni = 0; ni < 2; ++ni) {
      int col = n0 + wn + ni * 16 + l15;
      float bs = bias[col];
      #pragma unroll
      for (int r = 0; r < 4; ++r)
        epi_write<EPI, N>(acc[mi][ni][r] + bs, m0 + wm + mi * 16 + lg * 4 + r,
                          col, resid, out_f32, out_bf, q_out, vt_out);
    }
}

// ---------------- 128x64 tile, 8 waves, 3 blocks/CU (O, FC2) -----------------
// EPI=1 only (proven path): f32 out = resid + acc + bias.  Counted vmcnt(3).
template<int N, int K>
__global__ __launch_bounds__(512, 6) void gemm_n64(
    const unsigned short* __restrict__ A, const unsigned short* __restrict__ Bt,
    const float* __restrict__ bias, const float* resid, float* out_f32)
{
  __shared__ __align__(16) unsigned short As_[2][8192];   // 128x64
  __shared__ __align__(16) unsigned short Bs_[2][4096];   // 64x64
  constexpr int NTN = N >> 6;
  constexpr int NT = K >> 6;
  int m_t, n_t;
  band_map<NTN, 4>(blockIdx.x, gridDim.x, m_t, n_t);
  int m0 = m_t << 7, n0 = n_t << 6;
  int t = threadIdx.x, lane = t & 63, w = t >> 6;
  int l15 = lane & 15, lg = lane >> 4;
  int wm = (w >> 1) << 5;                       // 0/32/64/96
  int wn = (w & 1) << 5;                        // 0/32
  int lrow = lane >> 3;
  int lxor = ((lane & 7) ^ lrow) << 3;
  const unsigned short* Abase = A + (size_t)m0 * K;
  const unsigned short* Bbase = Bt + (size_t)n0 * K;

  auto stage = [&](int buf, int tile) {
    int k0 = tile << 6;
    #pragma unroll
    for (int j = 0; j < 2; ++j) {               // A: 2 loads/thread
      int row = j * 64 + w * 8 + lrow;
      g2l16(&Abase[(size_t)row * K + k0 + lxor], &As_[buf][(j * 512 + w * 64) * 8]);
    }
    int brow = w * 8 + lrow;                    // B: 1 load/thread
    g2l16(&Bbase[(size_t)brow * K + k0 + lxor], &Bs_[buf][w * 512]);
  };

  f32x4 acc[2][2] = {};
  stage(0, 0);
  asm volatile("s_waitcnt vmcnt(0)" ::: "memory");
  __builtin_amdgcn_sched_barrier(0);
  __builtin_amdgcn_s_barrier();

  int cswz = (l15 & 7) << 3;
  for (int tt = 0; tt < NT; ++tt) {
    int cur = tt & 1;
    if (tt + 1 < NT) {
      stage(cur ^ 1, tt + 1);
      asm volatile("s_waitcnt vmcnt(3)" ::: "memory");
    } else {
      asm volatile("s_waitcnt vmcnt(0)" ::: "memory");
    }
    __builtin_amdgcn_sched_barrier(0);
    __builtin_amdgcn_s_barrier();
    __builtin_amdgcn_sched_barrier(0);
    const unsigned short* Ac = &As_[cur][0];
    const unsigned short* Bc = &Bs_[cur][0];
    #pragma unroll
    for (int kk = 0; kk < 2; ++kk) {
      s8v a[2], b[2];
      int col = (kk * 32 + lg * 8) ^ cswz;
      #pragma unroll
      for (int i = 0; i < 2; ++i)
        a[i] = *(const s8v*)&Ac[(wm + i * 16 + l15) * 64 + col];
      #pragma unroll
      for (int i = 0; i < 2; ++i)
        b[i] = *(const s8v*)&Bc[(wn + i * 16 + l15) * 64 + col];
      __builtin_amdgcn_s_setprio(1);
      #pragma unroll
      for (int mi = 0; mi < 2; ++mi)
        #pragma unroll
        for (int ni = 0; ni < 2; ++ni)
          acc[mi][ni] = __builtin_amdgcn_mfma_f32_16x16x32_bf16(a[mi], b[ni], acc[mi][ni], 0, 0, 0);
      __builtin_amdgcn_s_setprio(0);
    }
    if (tt + 1 < NT) {
      __builtin_amdgcn_sched_barrier(0);
      __builtin_amdgcn_s_barrier();
      __builtin_amdgcn_sched_barrier(0);
    }
  }
  #pragma unroll
  for (int mi = 0; mi < 2; ++mi) {
    #pragma unroll
    for (int ni = 0; ni < 2; ++ni) {
      int col = n0 + wn + ni * 16 + l15;
      float bs = bias[col];
      #pragma unroll
      for (int r = 0; r < 4; ++r) {
        int row = m0 + wm + mi * 16 + lg * 4 + r;
        float v = acc[mi][ni][r] + bs;
        out_f32[(size_t)row * N + col] = resid[(size_t)row * N + col] + v;
      }
    }
  }
}

// ---------------- fused attention: staged K/V + counted vmcnt ---------------
// 768 blocks XCD-chunked; 4 waves x 32 q-cols; LDS 48 KiB -> 3 blocks/CU.
// Q in registers; per-wave Ps; stage(t+1) -> vmcnt(4) -> barrier -> compute.
__global__ __launch_bounds__(256, 3) void attn_kernel(
    const unsigned short* __restrict__ qk,  // [8192][768] (q == k, pre-scaled)
    const unsigned short* __restrict__ vt,  // [96][64][1024]
    unsigned short* __restrict__ o)         // [8192][768]
{
  __shared__ __align__(16) unsigned short Ks[2][64 * 64];
  __shared__ __align__(16) unsigned short Vs[2][64 * 64];
  __shared__ __align__(16) unsigned short Ps[4][32 * 64];
  int bid = blockIdx.x;
  int xcd = bid & 7, idx = bid >> 3;
  int bh = xcd * 12 + (idx >> 3), qt = idx & 7;
  int b = bh / 12, h = bh % 12;
  int t = threadIdx.x, lane = t & 63, w = t >> 6;
  int l15 = lane & 15, lg = lane >> 4;
  int wq0 = w << 5;
  size_t qrow0 = (size_t)b * 1024 + qt * 128;
  size_t krow0 = (size_t)b * 1024;
  size_t vbase = ((size_t)bh) * 64 * 1024;
  int cswz = (l15 & 7) << 3;
  unsigned short* myPs = &Ps[w][0];

  int srow = t >> 3;
  int scsw = ((t & 7) << 3) ^ ((srow & 7) << 3);
  const unsigned short* ksrc = &qk[(krow0 + srow) * 768 + h * 64 + scsw];
  const unsigned short* vsrc = &vt[vbase + (size_t)srow * 1024 + scsw];

  auto stage = [&](int buf, int kt) {
    const unsigned short* kp = ksrc + (size_t)kt * 64 * 768;
    const unsigned short* vp = vsrc + kt * 64;
    #pragma unroll
    for (int j = 0; j < 2; ++j) {               // 4 loads/thread
      g2l16(kp + (size_t)j * 32 * 768, &Ks[buf][(j * 256 + w * 64) * 8]);
      g2l16(vp + (size_t)j * 32 * 1024, &Vs[buf][(j * 256 + w * 64) * 8]);
    }
  };

  // Q fragments in registers (reused for all 16 K-tiles)
  s8v qf[2][2];
  #pragma unroll
  for (int ni = 0; ni < 2; ++ni)
    #pragma unroll
    for (int kk = 0; kk < 2; ++kk)
      qf[ni][kk] = *(const s8v*)&qk[(qrow0 + wq0 + ni * 16 + l15) * 768 +
                                    h * 64 + kk * 32 + lg * 8];

  f32x4 oacc[4][2] = {};
  float lsum[2] = {0.f, 0.f};

  stage(0, 0);
  asm volatile("s_waitcnt vmcnt(0)" ::: "memory");
  __builtin_amdgcn_sched_barrier(0);
  __builtin_amdgcn_s_barrier();

  for (int kt = 0; kt < 16; ++kt) {
    int buf = kt & 1;
    if (kt + 1 < 16) {
      stage(buf ^ 1, kt + 1);
      asm volatile("s_waitcnt vmcnt(4)" ::: "memory");
    } else {
      asm volatile("s_waitcnt vmcnt(0)" ::: "memory");
    }
    __builtin_amdgcn_sched_barrier(0);
    __builtin_amdgcn_s_barrier();          // stage(kt) landed block-wide
    __builtin_amdgcn_sched_barrier(0);
    const unsigned short* Kb = Ks[buf];
    const unsigned short* Vb = Vs[buf];
    f32x4 st[4][2] = {};
    #pragma unroll
    for (int kk = 0; kk < 2; ++kk) {
      int col = (kk * 32 + lg * 8) ^ cswz;
      s8v a[4];
      #pragma unroll
      for (int i = 0; i < 4; ++i) a[i] = *(const s8v*)&Kb[(i * 16 + l15) * 64 + col];
      #pragma unroll
      for (int mi = 0; mi < 4; ++mi)
        #pragma unroll
        for (int ni = 0; ni < 2; ++ni)
          st[mi][ni] = __builtin_amdgcn_mfma_f32_16x16x32_bf16(a[mi], qf[ni][kk], st[mi][ni], 0, 0, 0);
    }
    #pragma unroll
    for (int ni = 0; ni < 2; ++ni) {
      int prow = (ni * 16 + l15) * 64;
      #pragma unroll
      for (int mi = 0; mi < 4; ++mi) {
        float p0, p1, p2, p3;
        asm("v_exp_f32 %0, %1" : "=v"(p0) : "v"(st[mi][ni][0]));
        asm("v_exp_f32 %0, %1" : "=v"(p1) : "v"(st[mi][ni][1]));
        asm("v_exp_f32 %0, %1" : "=v"(p2) : "v"(st[mi][ni][2]));
        asm("v_exp_f32 %0, %1" : "=v"(p3) : "v"(st[mi][ni][3]));
        lsum[ni] += (p0 + p1) + (p2 + p3);
        unsigned lo, hi;
        asm("v_cvt_pk_bf16_f32 %0, %1, %2" : "=v"(lo) : "v"(p0), "v"(p1));
        asm("v_cvt_pk_bf16_f32 %0, %1, %2" : "=v"(hi) : "v"(p2), "v"(p3));
        unsigned long long pk = (unsigned long long)lo | ((unsigned long long)hi << 32);
        *(unsigned long long*)&myPs[prow + ((mi * 16 + lg * 4) ^ cswz)] = pk;
      }
    }
    #pragma unroll
    for (int kk = 0; kk < 2; ++kk) {
      int col = (kk * 32 + lg * 8) ^ cswz;
      s8v vv[4], bp[2];
      #pragma unroll
      for (int i = 0; i < 4; ++i) vv[i] = *(const s8v*)&Vb[(i * 16 + l15) * 64 + col];
      #pragma unroll
      for (int i = 0; i < 2; ++i) bp[i] = *(const s8v*)&myPs[(i * 16 + l15) * 64 + col];
      #pragma unroll
      for (int ei = 0; ei < 4; ++ei)
        #pragma unroll
        for (int ni = 0; ni < 2; ++ni)
          oacc[ei][ni] = __builtin_amdgcn_mfma_f32_16x16x32_bf16(vv[ei], bp[ni], oacc[ei][ni], 0, 0, 0);
    }
    if (kt + 1 < 16) {
      __builtin_amdgcn_sched_barrier(0);
      __builtin_amdgcn_s_barrier();        // reads of buf done block-wide
      __builtin_amdgcn_sched_barrier(0);
    }
  }
  #pragma unroll
  for (int ni = 0; ni < 2; ++ni) {
    float s = lsum[ni];
    s += __shfl_xor(s, 16);
    s += __shfl_xor(s, 32);
    float inv = 1.f / s;
    int q = wq0 + ni * 16 + l15;
    size_t obase = (qrow0 + q) * 768 + h * 64;
    #pragma unroll
    for (int ei = 0; ei < 4; ++ei) {
      us4v ov;
      #pragma unroll
      for (int r = 0; r < 4; ++r) ov[r] = f2b(oacc[ei][ni][r] * inv);
      *(us4v*)&o[obase + ei * 16 + lg * 4] = ov;
    }
  }
}

// ---------------------------------------------------------------------------
extern "C" void kernel_launch(void* const* d_in, const int* in_sizes, int n_in,
                              void* d_out, int out_size, void* d_ws, size_t ws_size,
                              hipStream_t stream)
{
  const float* x     = (const float*)d_in[0];
  const float* ln1_g = (const float*)d_in[1];
  const float* ln1_b = (const float*)d_in[2];
  const float* Wq    = (const float*)d_in[3];
  const float* bq    = (const float*)d_in[4];
  const float* Wv    = (const float*)d_in[5];
  const float* bv    = (const float*)d_in[6];
  const float* Wo    = (const float*)d_in[7];
  const float* bo    = (const float*)d_in[8];
  const float* ln2_g = (const float*)d_in[9];
  const float* ln2_b = (const float*)d_in[10];
  const float* W1    = (const float*)d_in[11];
  const float* b1    = (const float*)d_in[12];
  const float* W2    = (const float*)d_in[13];
  const float* b2    = (const float*)d_in[14];
  float* out = (float*)d_out;

  char* ws = (char*)d_ws;
  size_t off = 0;
  auto alloc = [&](size_t bytes) -> void* {
    void* p = ws + off; off += (bytes + 255) & ~(size_t)255; return p;
  };
  unsigned short* Wqv_t  = (unsigned short*)alloc(1536ull * 768 * 2);
  float*          bias_qv= (float*)         alloc(1536ull * 4);
  unsigned short* Wo_t   = (unsigned short*)alloc(768ull * 768 * 2);
  unsigned short* W1_t   = (unsigned short*)alloc(3072ull * 768 * 2);
  unsigned short* W2_t   = (unsigned short*)alloc(768ull * 3072 * 2);
  unsigned short* h_bf   = (unsigned short*)alloc(8192ull * 768 * 2);
  unsigned short* q_bf   = (unsigned short*)alloc(8192ull * 768 * 2);
  unsigned short* v_t    = (unsigned short*)alloc(96ull * 64 * 1024 * 2);
  unsigned short* o_bf   = (unsigned short*)alloc(8192ull * 768 * 2);
  unsigned short* h2_bf  = (unsigned short*)alloc(8192ull * 768 * 2);
  unsigned short* m1_bf  = (unsigned short*)alloc(8192ull * 3072 * 2);

  prep_kernel<<<17408, 256, 0, stream>>>(Wq, bq, Wv, bv, Wo, W1, W2,
                                         Wqv_t, bias_qv, Wo_t, W1_t, W2_t,
                                         x, ln1_g, ln1_b, h_bf);
  gemm128<3, 1536, 768><<<768, 512, 0, stream>>>(h_bf, Wqv_t, bias_qv,
      nullptr, nullptr, nullptr, q_bf, v_t);
  attn_kernel<<<768, 256, 0, stream>>>(q_bf, v_t, o_bf);
  gemm_n64<768, 768><<<768, 512, 0, stream>>>(o_bf, Wo_t, bo, x, out);
  ln_kernel<<<8192, 256, 0, stream>>>(out, ln2_g, ln2_b, h2_bf);
  gemm128<2, 3072, 768><<<1536, 512, 0, stream>>>(h2_bf, W1_t, b1,
      nullptr, nullptr, m1_bf, nullptr, nullptr);
  gemm_n64<768, 3072><<<768, 512, 0, stream>>>(m1_bf, W2_t, b2, out, out);
}